// Round 1
// baseline (3431.802 us; speedup 1.0000x reference)
//
#include <hip/hip_runtime.h>
#include <hip/hip_bf16.h>
#include <math.h>

#define EPS 1e-5f

// ---------------------------------------------------------------------------
// Global average pool: in [B,C,H,W] -> out [B*C] (mean over H*W)
// grid = B*C blocks, 256 threads
// ---------------------------------------------------------------------------
__global__ void pool_kernel(const float* __restrict__ in, float* __restrict__ out, int HW) {
    int bc = blockIdx.x;
    const float* p = in + (size_t)bc * HW;
    float s = 0.f;
    for (int i = threadIdx.x; i < HW; i += blockDim.x) s += p[i];
    #pragma unroll
    for (int off = 32; off; off >>= 1) s += __shfl_down(s, off);
    __shared__ float tmp[4];
    int lane = threadIdx.x & 63, w = threadIdx.x >> 6;
    if (!lane) tmp[w] = s;
    __syncthreads();
    if (!threadIdx.x) {
        s = tmp[0] + tmp[1] + tmp[2] + tmp[3];
        out[bc] = s / (float)HW;
    }
}

// ---------------------------------------------------------------------------
// Attention head (single block, 256 threads). B=16, A=16, K=4 fixed.
// pooled [B,C] -> ch_att [B,C], fl_att [B,Cout], sp_att [B,9], kn_att [B,4]
// ---------------------------------------------------------------------------
__device__ inline float sigmoidf_(float x) { return 1.f / (1.f + expf(-x)); }

__global__ void attn_kernel(const float* __restrict__ pooled,
                            const float* __restrict__ fc_w,
                            const float* __restrict__ bn_g, const float* __restrict__ bn_b,
                            const float* __restrict__ ch_w, const float* __restrict__ ch_b,
                            const float* __restrict__ fl_w, const float* __restrict__ fl_b,
                            const float* __restrict__ sp_w, const float* __restrict__ sp_b,
                            const float* __restrict__ kn_w, const float* __restrict__ kn_b,
                            float* __restrict__ ch_att, float* __restrict__ fl_att,
                            float* __restrict__ sp_att, float* __restrict__ kn_att,
                            int C, int Cout) {
    const int Bb = 16, A = 16, K = 4;
    __shared__ float h[16][16];   // [b][a]
    int tid = threadIdx.x;

    // h = pooled @ fc_w.T  (no bias)
    if (tid < Bb * A) {
        int b = tid >> 4, a = tid & 15;
        const float* pr = pooled + b * C;
        const float* fw = fc_w + a * C;
        float s = 0.f;
        for (int c = 0; c < C; c++) s += pr[c] * fw[c];
        h[b][a] = s;
    }
    __syncthreads();

    // BN over batch (train mode) + ReLU; thread a handles column a
    if (tid < A) {
        int a = tid;
        float m = 0.f;
        for (int b = 0; b < Bb; b++) m += h[b][a];
        m *= (1.f / 16.f);
        float v = 0.f;
        for (int b = 0; b < Bb; b++) { float d = h[b][a] - m; v += d * d; }
        v *= (1.f / 16.f);
        float inv = rsqrtf(v + EPS);
        float g = bn_g[a], bb = bn_b[a];
        for (int b = 0; b < Bb; b++) {
            float t = (h[b][a] - m) * inv * g + bb;
            h[b][a] = t > 0.f ? t : 0.f;
        }
    }
    __syncthreads();

    // channel attention [B,C]
    for (int idx = tid; idx < Bb * C; idx += blockDim.x) {
        int b = idx / C, c = idx % C;
        float s = ch_b[c];
        #pragma unroll
        for (int a = 0; a < A; a++) s += h[b][a] * ch_w[c * A + a];
        ch_att[idx] = sigmoidf_(s);
    }
    // filter attention [B,Cout]
    for (int idx = tid; idx < Bb * Cout; idx += blockDim.x) {
        int b = idx / Cout, o = idx % Cout;
        float s = fl_b[o];
        #pragma unroll
        for (int a = 0; a < A; a++) s += h[b][a] * fl_w[o * A + a];
        fl_att[idx] = sigmoidf_(s);
    }
    // spatial attention [B,9]
    for (int idx = tid; idx < Bb * 9; idx += blockDim.x) {
        int b = idx / 9, r = idx % 9;
        float s = sp_b[r];
        #pragma unroll
        for (int a = 0; a < A; a++) s += h[b][a] * sp_w[r * A + a];
        sp_att[idx] = sigmoidf_(s);
    }
    // kernel attention softmax [B,4]
    if (tid < Bb) {
        int b = tid;
        float l[K], mx = -1e30f;
        #pragma unroll
        for (int k = 0; k < K; k++) {
            float s = kn_b[k];
            #pragma unroll
            for (int a = 0; a < A; a++) s += h[b][a] * kn_w[k * A + a];
            l[k] = s; mx = fmaxf(mx, s);
        }
        float den = 0.f;
        #pragma unroll
        for (int k = 0; k < K; k++) { l[k] = expf(l[k] - mx); den += l[k]; }
        #pragma unroll
        for (int k = 0; k < K; k++) kn_att[b * K + k] = l[k] / den;
    }
}

// ---------------------------------------------------------------------------
// Effective weight aggregation:
// eff[b,o,i,rs] = fl[b,o]*ch[b,i]*sp[b,rs]* sum_k kn[b,k]*W[k,o,i,rs]
// ---------------------------------------------------------------------------
__global__ void wagg_kernel(const float* __restrict__ W, const float* __restrict__ ch,
                            const float* __restrict__ fl, const float* __restrict__ sp,
                            const float* __restrict__ kn, float* __restrict__ eff,
                            int Cout, int Cin, int N) {
    int idx = blockIdx.x * blockDim.x + threadIdx.x;
    if (idx >= N) return;
    int rs = idx % 9; int t = idx / 9;
    int i = t % Cin; t /= Cin;
    int o = t % Cout; int b = t / Cout;
    size_t kstride = (size_t)Cout * Cin * 9;
    const float* wp = W + ((size_t)o * Cin + i) * 9 + rs;
    const float* kp = kn + b * 4;
    float s = kp[0] * wp[0] + kp[1] * wp[kstride] + kp[2] * wp[2 * kstride] + kp[3] * wp[3 * kstride];
    eff[idx] = fl[b * Cout + o] * ch[b * Cin + i] * sp[b * 9 + rs] * s;
}

// ---------------------------------------------------------------------------
// Direct per-sample 3x3 conv, pad=1. Cout=128, H=W=128.
// grid (Cout/8, H, B), block 128 (one thread per x). Each thread computes
// 8 output channels at (y,x). Weight addresses are wave-uniform -> s_load.
// ---------------------------------------------------------------------------
__global__ __launch_bounds__(128) void conv_kernel(const float* __restrict__ xin,
                                                   const float* __restrict__ wef,
                                                   float* __restrict__ out, int Cin) {
    const int H = 128, W = 128, Cout = 128;
    int b = blockIdx.z, y = blockIdx.y, og = blockIdx.x;
    int xc = threadIdx.x;
    const float* xb = xin + (size_t)b * Cin * H * W;
    const float* wb = wef + (((size_t)b * Cout + og * 8) * Cin) * 9;
    float acc[8] = {0.f, 0.f, 0.f, 0.f, 0.f, 0.f, 0.f, 0.f};
    bool xl = xc > 0, xr = xc < W - 1;
    for (int i = 0; i < Cin; i++) {
        const float* base = xb + ((size_t)i * H + y) * W + xc;
        float xv[9];
        #pragma unroll
        for (int r = 0; r < 3; r++) {
            int yy = y + r - 1;
            bool yok = (unsigned)yy < (unsigned)H;
            const float* rp = base + (r - 1) * W;
            xv[r * 3 + 0] = (yok && xl) ? rp[-1] : 0.f;
            xv[r * 3 + 1] = yok ? rp[0] : 0.f;
            xv[r * 3 + 2] = (yok && xr) ? rp[1] : 0.f;
        }
        const float* wp = wb + i * 9;
        #pragma unroll
        for (int o = 0; o < 8; o++) {
            const float* w = wp + (size_t)o * Cin * 9;
            float a0 = acc[o];
            #pragma unroll
            for (int rs = 0; rs < 9; rs++) a0 = fmaf(xv[rs], w[rs], a0);
            acc[o] = a0;
        }
    }
    size_t ob = (((size_t)b * Cout + og * 8) * H + y) * W + xc;
    #pragma unroll
    for (int o = 0; o < 8; o++) out[ob + (size_t)o * H * W] = acc[o];
}

// ---------------------------------------------------------------------------
// BN stats (train mode): per-channel mean + inv-std over (B,H,W)
// grid = C blocks
// ---------------------------------------------------------------------------
__global__ void bnstat_kernel(const float* __restrict__ in, float* __restrict__ stats,
                              int B, int C, int HW) {
    int c = blockIdx.x;
    float s = 0.f, q = 0.f;
    for (int b = 0; b < B; b++) {
        const float* p = in + ((size_t)b * C + c) * HW;
        for (int i = threadIdx.x; i < HW; i += blockDim.x) {
            float v = p[i]; s += v; q += v * v;
        }
    }
    #pragma unroll
    for (int off = 32; off; off >>= 1) { s += __shfl_down(s, off); q += __shfl_down(q, off); }
    __shared__ float ss[4], qq[4];
    int lane = threadIdx.x & 63, w = threadIdx.x >> 6;
    if (!lane) { ss[w] = s; qq[w] = q; }
    __syncthreads();
    if (!threadIdx.x) {
        s = ss[0] + ss[1] + ss[2] + ss[3];
        q = qq[0] + qq[1] + qq[2] + qq[3];
        float n = (float)B * (float)HW;
        float m = s / n;
        float var = q / n - m * m;
        stats[2 * c] = m;
        stats[2 * c + 1] = rsqrtf(var + EPS);
    }
}

// ---------------------------------------------------------------------------
// BN apply + ReLU, in place
// ---------------------------------------------------------------------------
__global__ void bnapply_kernel(float* __restrict__ buf, const float* __restrict__ stats,
                               const float* __restrict__ g, const float* __restrict__ bta,
                               int C, int HW, size_t N) {
    size_t idx = (size_t)blockIdx.x * blockDim.x + threadIdx.x;
    size_t stride = (size_t)gridDim.x * blockDim.x;
    for (; idx < N; idx += stride) {
        int c = (int)((idx / (size_t)HW) % (size_t)C);
        float v = (buf[idx] - stats[2 * c]) * stats[2 * c + 1] * g[c] + bta[c];
        buf[idx] = v > 0.f ? v : 0.f;
    }
}

// ---------------------------------------------------------------------------
extern "C" void kernel_launch(void* const* d_in, const int* in_sizes, int n_in,
                              void* d_out, int out_size, void* d_ws, size_t ws_size,
                              hipStream_t stream) {
    const int B = 16, Cin1 = 64, C = 128, H = 128, W = 128, HW = H * W;

    const float* x      = (const float*)d_in[0];
    const float* w1     = (const float*)d_in[1];
    const float* a_fc_w = (const float*)d_in[2];
    const float* a_bn_g = (const float*)d_in[3];
    const float* a_bn_b = (const float*)d_in[4];
    const float* a_ch_w = (const float*)d_in[5];
    const float* a_ch_b = (const float*)d_in[6];
    const float* a_fl_w = (const float*)d_in[7];
    const float* a_fl_b = (const float*)d_in[8];
    const float* a_sp_w = (const float*)d_in[9];
    const float* a_sp_b = (const float*)d_in[10];
    const float* a_kn_w = (const float*)d_in[11];
    const float* a_kn_b = (const float*)d_in[12];
    const float* bn1_g  = (const float*)d_in[13];
    const float* bn1_b  = (const float*)d_in[14];
    const float* w2     = (const float*)d_in[15];
    const float* b_fc_w = (const float*)d_in[16];
    const float* b_bn_g = (const float*)d_in[17];
    const float* b_bn_b = (const float*)d_in[18];
    const float* b_ch_w = (const float*)d_in[19];
    const float* b_ch_b = (const float*)d_in[20];
    const float* b_fl_w = (const float*)d_in[21];
    const float* b_fl_b = (const float*)d_in[22];
    const float* b_sp_w = (const float*)d_in[23];
    const float* b_sp_b = (const float*)d_in[24];
    const float* b_kn_w = (const float*)d_in[25];
    const float* b_kn_b = (const float*)d_in[26];
    const float* bn2_g  = (const float*)d_in[27];
    const float* bn2_b  = (const float*)d_in[28];

    float* out = (float*)d_out;
    float* ws  = (float*)d_ws;

    const size_t BUF_N = (size_t)B * C * H * W;          // 33,554,432
    float* BUF  = ws;
    float* EFF  = BUF + BUF_N;                           // up to 16*128*128*9 = 2,359,296
    float* POOL = EFF + (size_t)B * C * C * 9;
    float* CH   = POOL + 2048;
    float* FL   = CH + 2048;
    float* SP   = FL + 2048;
    float* KN   = SP + 160;
    float* ST   = KN + 64;

    // ---------------- layer 1 (Cin=64 -> Cout=128) ----------------
    pool_kernel<<<B * Cin1, 256, 0, stream>>>(x, POOL, HW);
    attn_kernel<<<1, 256, 0, stream>>>(POOL, a_fc_w, a_bn_g, a_bn_b, a_ch_w, a_ch_b,
                                       a_fl_w, a_fl_b, a_sp_w, a_sp_b, a_kn_w, a_kn_b,
                                       CH, FL, SP, KN, Cin1, C);
    int N1 = B * C * Cin1 * 9;
    wagg_kernel<<<(N1 + 255) / 256, 256, 0, stream>>>(w1, CH, FL, SP, KN, EFF, C, Cin1, N1);
    conv_kernel<<<dim3(C / 8, H, B), 128, 0, stream>>>(x, EFF, BUF, Cin1);
    bnstat_kernel<<<C, 256, 0, stream>>>(BUF, ST, B, C, HW);
    bnapply_kernel<<<2048, 256, 0, stream>>>(BUF, ST, bn1_g, bn1_b, C, HW, BUF_N);

    // ---------------- layer 2 (Cin=128 -> Cout=128) ----------------
    pool_kernel<<<B * C, 256, 0, stream>>>(BUF, POOL, HW);
    attn_kernel<<<1, 256, 0, stream>>>(POOL, b_fc_w, b_bn_g, b_bn_b, b_ch_w, b_ch_b,
                                       b_fl_w, b_fl_b, b_sp_w, b_sp_b, b_kn_w, b_kn_b,
                                       CH, FL, SP, KN, C, C);
    int N2 = B * C * C * 9;
    wagg_kernel<<<(N2 + 255) / 256, 256, 0, stream>>>(w2, CH, FL, SP, KN, EFF, C, C, N2);
    conv_kernel<<<dim3(C / 8, H, B), 128, 0, stream>>>(BUF, EFF, out, C);
    bnstat_kernel<<<C, 256, 0, stream>>>(out, ST, B, C, HW);
    bnapply_kernel<<<2048, 256, 0, stream>>>(out, ST, bn2_g, bn2_b, C, HW, BUF_N);
}

// Round 2
// 1103.525 us; speedup vs baseline: 3.1099x; 3.1099x over previous
//
#include <hip/hip_runtime.h>
#include <hip/hip_bf16.h>
#include <math.h>

#define EPS 1e-5f

typedef __attribute__((ext_vector_type(8))) short bf16x8;
typedef __attribute__((ext_vector_type(4))) float f32x4;

__device__ inline ushort f2bf(float f) {
    uint u = __float_as_uint(f);
    uint r = (u + 0x7fffu + ((u >> 16) & 1u)) >> 16;
    return (ushort)r;
}
__device__ inline float bf2f(ushort u) {
    return __uint_as_float(((uint)u) << 16);
}
__device__ inline float sigmoidf_(float x) { return 1.f / (1.f + expf(-x)); }

// ---------------------------------------------------------------------------
// Global avg pool (NCHW fp32): out[b*C+c] = mean over H*W. grid = B*C.
// ---------------------------------------------------------------------------
__global__ void pool_kernel(const float* __restrict__ in, float* __restrict__ out, int HW) {
    int bc = blockIdx.x;
    const float* p = in + (size_t)bc * HW;
    float s = 0.f;
    for (int i = threadIdx.x; i < HW; i += blockDim.x) s += p[i];
    #pragma unroll
    for (int off = 32; off; off >>= 1) s += __shfl_down(s, off);
    __shared__ float tmp[4];
    int lane = threadIdx.x & 63, w = threadIdx.x >> 6;
    if (!lane) tmp[w] = s;
    __syncthreads();
    if (!threadIdx.x) {
        s = tmp[0] + tmp[1] + tmp[2] + tmp[3];
        out[bc] = s / (float)HW;
    }
}

// ---------------------------------------------------------------------------
// Partial pool over NHWC bf16 (layer 2). grid (B, 16), block 256.
// part[b][k][c] = sum over 1024 pixels.
// ---------------------------------------------------------------------------
__global__ void pool2_kernel(const ushort* __restrict__ xT, float* __restrict__ part) {
    int b = blockIdx.x, k = blockIdx.y;
    int t = threadIdx.x;
    int c = t & 127, sub = t >> 7;
    const ushort* src = xT + ((size_t)b * 16384 + k * 1024) * 128 + c;
    float s = 0.f;
    for (int j = sub; j < 1024; j += 2) s += bf2f(src[(size_t)j * 128]);
    __shared__ float red[128];
    if (sub) red[c] = s;
    __syncthreads();
    if (!sub) part[(b * 16 + k) * 128 + c] = s + red[c];
}

__global__ void pool2red_kernel(const float* __restrict__ part, float* __restrict__ pool, int n) {
    int idx = blockIdx.x * blockDim.x + threadIdx.x;
    if (idx >= n) return;
    int b = idx >> 7, c = idx & 127;
    float s = 0.f;
    #pragma unroll
    for (int k = 0; k < 16; k++) s += part[(b * 16 + k) * 128 + c];
    pool[idx] = s * (1.f / 16384.f);
}

// ---------------------------------------------------------------------------
// Attention head (single block, 256 threads). B=16, A=16, K=4 fixed.
// ---------------------------------------------------------------------------
__global__ void attn_kernel(const float* __restrict__ pooled,
                            const float* __restrict__ fc_w,
                            const float* __restrict__ bn_g, const float* __restrict__ bn_b,
                            const float* __restrict__ ch_w, const float* __restrict__ ch_b,
                            const float* __restrict__ fl_w, const float* __restrict__ fl_b,
                            const float* __restrict__ sp_w, const float* __restrict__ sp_b,
                            const float* __restrict__ kn_w, const float* __restrict__ kn_b,
                            float* __restrict__ ch_att, float* __restrict__ fl_att,
                            float* __restrict__ sp_att, float* __restrict__ kn_att,
                            int C, int Cout) {
    const int Bb = 16, A = 16, K = 4;
    __shared__ float h[16][16];
    int tid = threadIdx.x;

    if (tid < Bb * A) {
        int b = tid >> 4, a = tid & 15;
        const float* pr = pooled + b * C;
        const float* fw = fc_w + a * C;
        float s = 0.f;
        for (int c = 0; c < C; c++) s += pr[c] * fw[c];
        h[b][a] = s;
    }
    __syncthreads();

    if (tid < A) {
        int a = tid;
        float m = 0.f;
        for (int b = 0; b < Bb; b++) m += h[b][a];
        m *= (1.f / 16.f);
        float v = 0.f;
        for (int b = 0; b < Bb; b++) { float d = h[b][a] - m; v += d * d; }
        v *= (1.f / 16.f);
        float inv = rsqrtf(v + EPS);
        float g = bn_g[a], bb = bn_b[a];
        for (int b = 0; b < Bb; b++) {
            float t = (h[b][a] - m) * inv * g + bb;
            h[b][a] = t > 0.f ? t : 0.f;
        }
    }
    __syncthreads();

    for (int idx = tid; idx < Bb * C; idx += blockDim.x) {
        int b = idx / C, c = idx % C;
        float s = ch_b[c];
        #pragma unroll
        for (int a = 0; a < A; a++) s += h[b][a] * ch_w[c * A + a];
        ch_att[idx] = sigmoidf_(s);
    }
    for (int idx = tid; idx < Bb * Cout; idx += blockDim.x) {
        int b = idx / Cout, o = idx % Cout;
        float s = fl_b[o];
        #pragma unroll
        for (int a = 0; a < A; a++) s += h[b][a] * fl_w[o * A + a];
        fl_att[idx] = sigmoidf_(s);
    }
    for (int idx = tid; idx < Bb * 9; idx += blockDim.x) {
        int b = idx / 9, r = idx % 9;
        float s = sp_b[r];
        #pragma unroll
        for (int a = 0; a < A; a++) s += h[b][a] * sp_w[r * A + a];
        sp_att[idx] = sigmoidf_(s);
    }
    if (tid < Bb) {
        int b = tid;
        float l[K], mx = -1e30f;
        #pragma unroll
        for (int k = 0; k < K; k++) {
            float s = kn_b[k];
            #pragma unroll
            for (int a = 0; a < A; a++) s += h[b][a] * kn_w[k * A + a];
            l[k] = s; mx = fmaxf(mx, s);
        }
        float den = 0.f;
        #pragma unroll
        for (int k = 0; k < K; k++) { l[k] = expf(l[k] - mx); den += l[k]; }
        #pragma unroll
        for (int k = 0; k < K; k++) kn_att[b * K + k] = l[k] / den;
    }
}

// ---------------------------------------------------------------------------
// Effective weight aggregation -> bf16 in MFMA-fragment order:
// WbF[(((b*NT + t)*8 + ot)*64 + lane)*8 + e] holds
//   eff_w[b, o=ot*16+(lane&15), k=t*32+(lane>>4)*8+e],  k = rs*Cin + i
// eff = fl[b,o]*ch[b,i]*sp[b,rs]* sum_kn kn[b,kn]*W[kn,o,i,rs]
// ---------------------------------------------------------------------------
__global__ void waggF_kernel(const float* __restrict__ W4, const float* __restrict__ ch,
                             const float* __restrict__ fl, const float* __restrict__ sp,
                             const float* __restrict__ kn, ushort* __restrict__ WbF,
                             int Cout, int Cin, int NT, int N) {
    int idx = blockIdx.x * blockDim.x + threadIdx.x;
    if (idx >= N) return;
    int e = idx & 7;
    int l = (idx >> 3) & 63;
    int ot = (idx >> 9) & 7;
    int tb = idx >> 12;
    int t = tb % NT, b = tb / NT;
    int o = ot * 16 + (l & 15);
    int k = t * 32 + ((l >> 4) << 3) + e;
    int rs = k / Cin, i = k - rs * Cin;
    size_t kstride = (size_t)Cout * Cin * 9;
    const float* wp = W4 + ((size_t)o * Cin + i) * 9 + rs;
    const float* kp = kn + b * 4;
    float s = kp[0] * wp[0] + kp[1] * wp[kstride] + kp[2] * wp[2 * kstride] + kp[3] * wp[3 * kstride];
    float v = fl[b * Cout + o] * ch[b * Cin + i] * sp[b * 9 + rs] * s;
    WbF[idx] = f2bf(v);
}

// ---------------------------------------------------------------------------
// NCHW fp32 -> NHWC bf16 tiled transpose, optional BN(train stats)+ReLU.
// grid ((C/32)*(W/32), H, B), block 256. stats[2c]=mean, stats[2c+1]=invstd.
// ---------------------------------------------------------------------------
__global__ __launch_bounds__(256) void trans_kernel(const float* __restrict__ in,
                                                    ushort* __restrict__ out,
                                                    const float* __restrict__ stats,
                                                    const float* __restrict__ g,
                                                    const float* __restrict__ beta,
                                                    int C, int doBN) {
    int tilesC = C >> 5;
    int cb = (blockIdx.x % tilesC) << 5;
    int pb = (blockIdx.x / tilesC) << 5;
    int y = blockIdx.y, b = blockIdx.z;
    __shared__ float tile[32][33];
    int t = threadIdx.x;
    int p = t & 31, c0 = t >> 5;
    #pragma unroll
    for (int j = 0; j < 4; j++) {
        int cl = c0 + j * 8;
        int c = cb + cl;
        float v = in[(((size_t)b * C + c) * 128 + y) * 128 + pb + p];
        if (doBN) {
            v = (v - stats[2 * c]) * stats[2 * c + 1] * g[c] + beta[c];
            v = fmaxf(v, 0.f);
        }
        tile[cl][p] = v;
    }
    __syncthreads();
    int c2 = (t & 15) << 1, pp = t >> 4;
    #pragma unroll
    for (int j = 0; j < 2; j++) {
        int p2 = pp + j * 16;
        uint lo = f2bf(tile[c2][p2]);
        uint hi = f2bf(tile[c2 + 1][p2]);
        *(uint*)&out[(((size_t)b * 128 + y) * 128 + pb + p2) * C + cb + c2] = lo | (hi << 16);
    }
}

// ---------------------------------------------------------------------------
// Implicit-GEMM conv 3x3 pad 1 via MFMA.
// xT: [B][H][W][Cin] bf16 (NHWC). WbF: fragment-ordered weights (see waggF).
// out: [B][128][H][W] fp32 NCHW.
// Block = one (b,y): 128 out channels x 128 pixels. 256 threads = 4 waves,
// wave (wm,wn) owns 64x64. K = 9*Cin, rs-major, staged per 64-channel chunk.
// ---------------------------------------------------------------------------
__global__ __launch_bounds__(256, 2) void conv_mfma(const ushort* __restrict__ xT,
                                                    const ushort* __restrict__ WbF,
                                                    float* __restrict__ out,
                                                    int Cin) {
    const int Cpad = 72;                    // 64-channel chunk + 8 pad (16B-aligned rows)
    __shared__ short sx[3 * 130 * Cpad];    // 56,160 B -> 2 blocks/CU
    int y = blockIdx.x, b = blockIdx.y;
    int tid = threadIdx.x;
    int lane = tid & 63, wid = tid >> 6;
    int wm = wid >> 1, wn = wid & 1;
    int NT = (9 * Cin) >> 5;
    int Cdiv32 = Cin >> 5;

    f32x4 acc[4][4] = {};

    // zero whole LDS once (pads + OOB rows stay zero)
    {
        bf16x8 z = {};
        for (int e = tid * 8; e < 3 * 130 * Cpad; e += 256 * 8)
            *(bf16x8*)&sx[e] = z;
    }
    __syncthreads();

    const bf16x8* Ab = (const bf16x8*)WbF;
    size_t abase = (size_t)b * NT;

    for (int ch = 0; ch < Cin; ch += 64) {
        // stage chunk: rows y-1..y+1, cols -1..128 (pads already zero)
        for (int r = 0; r < 3; r++) {
            int yy = y + r - 1;
            if ((unsigned)yy < 128u) {
                const ushort* src = xT + ((size_t)(b * 128 + yy) * 128) * Cin + ch;
                for (int c8 = tid; c8 < 1024; c8 += 256) {
                    int p = c8 >> 3;
                    int i8 = (c8 & 7) << 3;
                    *(bf16x8*)&sx[(r * 130 + p + 1) * Cpad + i8] =
                        *(const bf16x8*)&src[p * Cin + i8];
                }
            }
        }
        __syncthreads();

        int chs = ch >> 5;
        for (int rs = 0; rs < 9; rs++) {
            int rrow = (rs / 3) * 130;
            int dx = rs % 3 - 1;
            int plbase = rrow + wn * 64 + (lane & 15) + dx + 1;
            #pragma unroll
            for (int ic2 = 0; ic2 < 2; ic2++) {
                int t = rs * Cdiv32 + chs + ic2;
                bf16x8 a[4], bv[4];
                size_t ai = ((abase + t) * 8 + wm * 4) * 64 + lane;
                #pragma unroll
                for (int m = 0; m < 4; m++) a[m] = Ab[ai + (size_t)m * 64];
                int c = (ic2 << 5) + ((lane >> 4) << 3);
                #pragma unroll
                for (int n = 0; n < 4; n++)
                    bv[n] = *(const bf16x8*)&sx[(plbase + n * 16) * Cpad + c];
                #pragma unroll
                for (int m = 0; m < 4; m++)
                    #pragma unroll
                    for (int n = 0; n < 4; n++)
                        acc[m][n] = __builtin_amdgcn_mfma_f32_16x16x32_bf16(
                            a[m], bv[n], acc[m][n], 0, 0, 0);
            }
        }
        __syncthreads();
    }

    // epilogue: D row=(lane>>4)*4+r (o), col=lane&15 (p)
    float* ob = out + ((size_t)b * 128) * 16384 + (size_t)y * 128 + wn * 64 + (lane & 15);
    int orow0 = wm * 64 + ((lane >> 4) << 2);
    #pragma unroll
    for (int m = 0; m < 4; m++)
        #pragma unroll
        for (int r = 0; r < 4; r++) {
            float* po = ob + (size_t)(orow0 + m * 16 + r) * 16384;
            #pragma unroll
            for (int n = 0; n < 4; n++) po[n * 16] = acc[m][n][r];
        }
}

// ---------------------------------------------------------------------------
// BN stats (train): per-channel mean + inv-std over (B,H,W). grid = C.
// ---------------------------------------------------------------------------
__global__ void bnstat_kernel(const float* __restrict__ in, float* __restrict__ stats,
                              int B, int C, int HW) {
    int c = blockIdx.x;
    float s = 0.f, q = 0.f;
    for (int b = 0; b < B; b++) {
        const float* p = in + ((size_t)b * C + c) * HW;
        for (int i = threadIdx.x; i < HW; i += blockDim.x) {
            float v = p[i]; s += v; q += v * v;
        }
    }
    #pragma unroll
    for (int off = 32; off; off >>= 1) { s += __shfl_down(s, off); q += __shfl_down(q, off); }
    __shared__ float ss[4], qq[4];
    int lane = threadIdx.x & 63, w = threadIdx.x >> 6;
    if (!lane) { ss[w] = s; qq[w] = q; }
    __syncthreads();
    if (!threadIdx.x) {
        s = ss[0] + ss[1] + ss[2] + ss[3];
        q = qq[0] + qq[1] + qq[2] + qq[3];
        float n = (float)B * (float)HW;
        float m = s / n;
        float var = q / n - m * m;
        stats[2 * c] = m;
        stats[2 * c + 1] = rsqrtf(var + EPS);
    }
}

// ---------------------------------------------------------------------------
// BN apply + ReLU in place (fp32 NCHW)
// ---------------------------------------------------------------------------
__global__ void bnapply_kernel(float* __restrict__ buf, const float* __restrict__ stats,
                               const float* __restrict__ g, const float* __restrict__ bta,
                               int C, int HW, size_t N) {
    size_t idx = (size_t)blockIdx.x * blockDim.x + threadIdx.x;
    size_t stride = (size_t)gridDim.x * blockDim.x;
    for (; idx < N; idx += stride) {
        int c = (int)((idx / (size_t)HW) % (size_t)C);
        float v = (buf[idx] - stats[2 * c]) * stats[2 * c + 1] * g[c] + bta[c];
        buf[idx] = v > 0.f ? v : 0.f;
    }
}

// ---------------------------------------------------------------------------
extern "C" void kernel_launch(void* const* d_in, const int* in_sizes, int n_in,
                              void* d_out, int out_size, void* d_ws, size_t ws_size,
                              hipStream_t stream) {
    const int B = 16, Cin1 = 64, C = 128, H = 128, W = 128, HW = H * W;

    const float* x      = (const float*)d_in[0];
    const float* w1     = (const float*)d_in[1];
    const float* a_fc_w = (const float*)d_in[2];
    const float* a_bn_g = (const float*)d_in[3];
    const float* a_bn_b = (const float*)d_in[4];
    const float* a_ch_w = (const float*)d_in[5];
    const float* a_ch_b = (const float*)d_in[6];
    const float* a_fl_w = (const float*)d_in[7];
    const float* a_fl_b = (const float*)d_in[8];
    const float* a_sp_w = (const float*)d_in[9];
    const float* a_sp_b = (const float*)d_in[10];
    const float* a_kn_w = (const float*)d_in[11];
    const float* a_kn_b = (const float*)d_in[12];
    const float* bn1_g  = (const float*)d_in[13];
    const float* bn1_b  = (const float*)d_in[14];
    const float* w2     = (const float*)d_in[15];
    const float* b_fc_w = (const float*)d_in[16];
    const float* b_bn_g = (const float*)d_in[17];
    const float* b_bn_b = (const float*)d_in[18];
    const float* b_ch_w = (const float*)d_in[19];
    const float* b_ch_b = (const float*)d_in[20];
    const float* b_fl_w = (const float*)d_in[21];
    const float* b_fl_b = (const float*)d_in[22];
    const float* b_sp_w = (const float*)d_in[23];
    const float* b_sp_b = (const float*)d_in[24];
    const float* b_kn_w = (const float*)d_in[25];
    const float* b_kn_b = (const float*)d_in[26];
    const float* bn2_g  = (const float*)d_in[27];
    const float* bn2_b  = (const float*)d_in[28];

    float* out = (float*)d_out;
    float* ws  = (float*)d_ws;

    // workspace layout (floats)
    float* XTf  = ws;                                // NHWC bf16 region (<=33.5M ushort)
    ushort* xT  = (ushort*)XTf;
    float* WBf  = XTf + 16777216;
    ushort* WbF = (ushort*)WBf;
    float* POOL = WBf + 1179648;
    float* PART = POOL + 2048;                       // 16*16*128 = 32768
    float* CH   = PART + 32768;
    float* FL   = CH + 2048;
    float* SP   = FL + 2048;
    float* KN   = SP + 160;
    float* ST   = KN + 64;

    // ---------------- layer 1 (Cin=64 -> Cout=128) ----------------
    trans_kernel<<<dim3((Cin1 / 32) * 4, H, B), 256, 0, stream>>>(x, xT, ST, nullptr, nullptr, Cin1, 0);
    pool_kernel<<<B * Cin1, 256, 0, stream>>>(x, POOL, HW);
    attn_kernel<<<1, 256, 0, stream>>>(POOL, a_fc_w, a_bn_g, a_bn_b, a_ch_w, a_ch_b,
                                       a_fl_w, a_fl_b, a_sp_w, a_sp_b, a_kn_w, a_kn_b,
                                       CH, FL, SP, KN, Cin1, C);
    int NT1 = 9 * Cin1 / 32;                         // 18
    int N1 = B * NT1 * 4096;
    waggF_kernel<<<(N1 + 255) / 256, 256, 0, stream>>>(w1, CH, FL, SP, KN, WbF, C, Cin1, NT1, N1);
    conv_mfma<<<dim3(H, B), 256, 0, stream>>>(xT, WbF, out, Cin1);     // out as scratch
    bnstat_kernel<<<C, 256, 0, stream>>>(out, ST, B, C, HW);
    // BN1+ReLU fused into transpose -> layer-2 NHWC bf16 input
    trans_kernel<<<dim3((C / 32) * 4, H, B), 256, 0, stream>>>(out, xT, ST, bn1_g, bn1_b, C, 1);

    // ---------------- layer 2 (Cin=128 -> Cout=128) ----------------
    pool2_kernel<<<dim3(B, 16), 256, 0, stream>>>(xT, PART);
    pool2red_kernel<<<(B * C + 255) / 256, 256, 0, stream>>>(PART, POOL, B * C);
    attn_kernel<<<1, 256, 0, stream>>>(POOL, b_fc_w, b_bn_g, b_bn_b, b_ch_w, b_ch_b,
                                       b_fl_w, b_fl_b, b_sp_w, b_sp_b, b_kn_w, b_kn_b,
                                       CH, FL, SP, KN, C, C);
    int NT2 = 9 * C / 32;                            // 36
    int N2 = B * NT2 * 4096;
    waggF_kernel<<<(N2 + 255) / 256, 256, 0, stream>>>(w2, CH, FL, SP, KN, WbF, C, C, NT2, N2);
    conv_mfma<<<dim3(H, B), 256, 0, stream>>>(xT, WbF, out, C);
    bnstat_kernel<<<C, 256, 0, stream>>>(out, ST, B, C, HW);
    bnapply_kernel<<<2048, 256, 0, stream>>>(out, ST, bn2_g, bn2_b, C, HW, (size_t)B * C * HW);
}

// Round 3
// 556.280 us; speedup vs baseline: 6.1692x; 1.9838x over previous
//
#include <hip/hip_runtime.h>
#include <hip/hip_bf16.h>
#include <math.h>

#define EPS 1e-5f

typedef __attribute__((ext_vector_type(8))) short bf16x8;
typedef __attribute__((ext_vector_type(4))) float f32x4;

__device__ inline ushort f2bf(float f) {
    uint u = __float_as_uint(f);
    uint r = (u + 0x7fffu + ((u >> 16) & 1u)) >> 16;
    return (ushort)r;
}
__device__ inline float bf2f(ushort u) {
    return __uint_as_float(((uint)u) << 16);
}
__device__ inline float sigmoidf_(float x) { return 1.f / (1.f + expf(-x)); }

// ---------------------------------------------------------------------------
// Global avg pool (NCHW fp32): out[b*C+c] = mean over H*W. grid = B*C.
// ---------------------------------------------------------------------------
__global__ void pool_kernel(const float* __restrict__ in, float* __restrict__ out, int HW) {
    int bc = blockIdx.x;
    const float* p = in + (size_t)bc * HW;
    float s = 0.f;
    for (int i = threadIdx.x; i < HW; i += blockDim.x) s += p[i];
    #pragma unroll
    for (int off = 32; off; off >>= 1) s += __shfl_down(s, off);
    __shared__ float tmp[4];
    int lane = threadIdx.x & 63, w = threadIdx.x >> 6;
    if (!lane) tmp[w] = s;
    __syncthreads();
    if (!threadIdx.x) {
        s = tmp[0] + tmp[1] + tmp[2] + tmp[3];
        out[bc] = s / (float)HW;
    }
}

// ---------------------------------------------------------------------------
// Partial pool over NHWC bf16 (layer 2). grid (B, 16), block 256.
// ---------------------------------------------------------------------------
__global__ void pool2_kernel(const ushort* __restrict__ xT, float* __restrict__ part) {
    int b = blockIdx.x, k = blockIdx.y;
    int t = threadIdx.x;
    int c = t & 127, sub = t >> 7;
    const ushort* src = xT + ((size_t)b * 16384 + k * 1024) * 128 + c;
    float s = 0.f;
    for (int j = sub; j < 1024; j += 2) s += bf2f(src[(size_t)j * 128]);
    __shared__ float red[128];
    if (sub) red[c] = s;
    __syncthreads();
    if (!sub) part[(b * 16 + k) * 128 + c] = s + red[c];
}

__global__ void pool2red_kernel(const float* __restrict__ part, float* __restrict__ pool, int n) {
    int idx = blockIdx.x * blockDim.x + threadIdx.x;
    if (idx >= n) return;
    int b = idx >> 7, c = idx & 127;
    float s = 0.f;
    #pragma unroll
    for (int k = 0; k < 16; k++) s += part[(b * 16 + k) * 128 + c];
    pool[idx] = s * (1.f / 16384.f);
}

// ---------------------------------------------------------------------------
// Attention head (single block, 256 threads). B=16, A=16, K=4 fixed.
// ---------------------------------------------------------------------------
__global__ void attn_kernel(const float* __restrict__ pooled,
                            const float* __restrict__ fc_w,
                            const float* __restrict__ bn_g, const float* __restrict__ bn_b,
                            const float* __restrict__ ch_w, const float* __restrict__ ch_b,
                            const float* __restrict__ fl_w, const float* __restrict__ fl_b,
                            const float* __restrict__ sp_w, const float* __restrict__ sp_b,
                            const float* __restrict__ kn_w, const float* __restrict__ kn_b,
                            float* __restrict__ ch_att, float* __restrict__ fl_att,
                            float* __restrict__ sp_att, float* __restrict__ kn_att,
                            int C, int Cout) {
    const int Bb = 16, A = 16, K = 4;
    __shared__ float h[16][16];
    int tid = threadIdx.x;

    if (tid < Bb * A) {
        int b = tid >> 4, a = tid & 15;
        const float* pr = pooled + b * C;
        const float* fw = fc_w + a * C;
        float s = 0.f;
        for (int c = 0; c < C; c++) s += pr[c] * fw[c];
        h[b][a] = s;
    }
    __syncthreads();

    if (tid < A) {
        int a = tid;
        float m = 0.f;
        for (int b = 0; b < Bb; b++) m += h[b][a];
        m *= (1.f / 16.f);
        float v = 0.f;
        for (int b = 0; b < Bb; b++) { float d = h[b][a] - m; v += d * d; }
        v *= (1.f / 16.f);
        float inv = rsqrtf(v + EPS);
        float g = bn_g[a], bb = bn_b[a];
        for (int b = 0; b < Bb; b++) {
            float t = (h[b][a] - m) * inv * g + bb;
            h[b][a] = t > 0.f ? t : 0.f;
        }
    }
    __syncthreads();

    for (int idx = tid; idx < Bb * C; idx += blockDim.x) {
        int b = idx / C, c = idx % C;
        float s = ch_b[c];
        #pragma unroll
        for (int a = 0; a < A; a++) s += h[b][a] * ch_w[c * A + a];
        ch_att[idx] = sigmoidf_(s);
    }
    for (int idx = tid; idx < Bb * Cout; idx += blockDim.x) {
        int b = idx / Cout, o = idx % Cout;
        float s = fl_b[o];
        #pragma unroll
        for (int a = 0; a < A; a++) s += h[b][a] * fl_w[o * A + a];
        fl_att[idx] = sigmoidf_(s);
    }
    for (int idx = tid; idx < Bb * 9; idx += blockDim.x) {
        int b = idx / 9, r = idx % 9;
        float s = sp_b[r];
        #pragma unroll
        for (int a = 0; a < A; a++) s += h[b][a] * sp_w[r * A + a];
        sp_att[idx] = sigmoidf_(s);
    }
    if (tid < Bb) {
        int b = tid;
        float l[K], mx = -1e30f;
        #pragma unroll
        for (int k = 0; k < K; k++) {
            float s = kn_b[k];
            #pragma unroll
            for (int a = 0; a < A; a++) s += h[b][a] * kn_w[k * A + a];
            l[k] = s; mx = fmaxf(mx, s);
        }
        float den = 0.f;
        #pragma unroll
        for (int k = 0; k < K; k++) { l[k] = expf(l[k] - mx); den += l[k]; }
        #pragma unroll
        for (int k = 0; k < K; k++) kn_att[b * K + k] = l[k] / den;
    }
}

// ---------------------------------------------------------------------------
// Effective weight aggregation -> bf16 in MFMA-fragment order.
// ---------------------------------------------------------------------------
__global__ void waggF_kernel(const float* __restrict__ W4, const float* __restrict__ ch,
                             const float* __restrict__ fl, const float* __restrict__ sp,
                             const float* __restrict__ kn, ushort* __restrict__ WbF,
                             int Cout, int Cin, int NT, int N) {
    int idx = blockIdx.x * blockDim.x + threadIdx.x;
    if (idx >= N) return;
    int e = idx & 7;
    int l = (idx >> 3) & 63;
    int ot = (idx >> 9) & 7;
    int tb = idx >> 12;
    int t = tb % NT, b = tb / NT;
    int o = ot * 16 + (l & 15);
    int k = t * 32 + ((l >> 4) << 3) + e;
    int rs = k / Cin, i = k - rs * Cin;
    size_t kstride = (size_t)Cout * Cin * 9;
    const float* wp = W4 + ((size_t)o * Cin + i) * 9 + rs;
    const float* kp = kn + b * 4;
    float s = kp[0] * wp[0] + kp[1] * wp[kstride] + kp[2] * wp[2 * kstride] + kp[3] * wp[3 * kstride];
    float v = fl[b * Cout + o] * ch[b * Cin + i] * sp[b * 9 + rs] * s;
    WbF[idx] = f2bf(v);
}

// ---------------------------------------------------------------------------
// NCHW fp32 -> NHWC bf16 tiled transpose, optional BN(train stats)+ReLU.
// ---------------------------------------------------------------------------
__global__ __launch_bounds__(256) void trans_kernel(const float* __restrict__ in,
                                                    ushort* __restrict__ out,
                                                    const float* __restrict__ stats,
                                                    const float* __restrict__ g,
                                                    const float* __restrict__ beta,
                                                    int C, int doBN) {
    int tilesC = C >> 5;
    int cb = (blockIdx.x % tilesC) << 5;
    int pb = (blockIdx.x / tilesC) << 5;
    int y = blockIdx.y, b = blockIdx.z;
    __shared__ float tile[32][33];
    int t = threadIdx.x;
    int p = t & 31, c0 = t >> 5;
    #pragma unroll
    for (int j = 0; j < 4; j++) {
        int cl = c0 + j * 8;
        int c = cb + cl;
        float v = in[(((size_t)b * C + c) * 128 + y) * 128 + pb + p];
        if (doBN) {
            v = (v - stats[2 * c]) * stats[2 * c + 1] * g[c] + beta[c];
            v = fmaxf(v, 0.f);
        }
        tile[cl][p] = v;
    }
    __syncthreads();
    int c2 = (t & 15) << 1, pp = t >> 4;
    #pragma unroll
    for (int j = 0; j < 2; j++) {
        int p2 = pp + j * 16;
        uint lo = f2bf(tile[c2][p2]);
        uint hi = f2bf(tile[c2 + 1][p2]);
        *(uint*)&out[(((size_t)b * 128 + y) * 128 + pb + p2) * C + cb + c2] = lo | (hi << 16);
    }
}

// ---------------------------------------------------------------------------
// Implicit-GEMM conv 3x3 pad 1 via MFMA + fused per-block BN partial stats.
// xT: [B][H][W][Cin] bf16 NHWC. WbF: fragment-ordered weights.
// out: [B][128][H][W] fp32 NCHW. part: [B*H][256] = per-block {sum,sumsq} per ch.
// ---------------------------------------------------------------------------
__global__ __launch_bounds__(256, 2) void conv_mfma(const ushort* __restrict__ xT,
                                                    const ushort* __restrict__ WbF,
                                                    float* __restrict__ out,
                                                    float* __restrict__ part,
                                                    int Cin) {
    const int Cpad = 72;
    __shared__ short sx[3 * 130 * Cpad];    // 56,160 B
    __shared__ float sred[4][64][2];        // +2 KB
    int y = blockIdx.x, b = blockIdx.y;
    int tid = threadIdx.x;
    int lane = tid & 63, wid = tid >> 6;
    int wm = wid >> 1, wn = wid & 1;
    int NT = (9 * Cin) >> 5;
    int Cdiv32 = Cin >> 5;

    f32x4 acc[4][4] = {};

    {
        bf16x8 z = {};
        for (int e = tid * 8; e < 3 * 130 * Cpad; e += 256 * 8)
            *(bf16x8*)&sx[e] = z;
    }
    __syncthreads();

    const bf16x8* Ab = (const bf16x8*)WbF;
    size_t abase = (size_t)b * NT;

    for (int ch = 0; ch < Cin; ch += 64) {
        for (int r = 0; r < 3; r++) {
            int yy = y + r - 1;
            if ((unsigned)yy < 128u) {
                const ushort* src = xT + ((size_t)(b * 128 + yy) * 128) * Cin + ch;
                for (int c8 = tid; c8 < 1024; c8 += 256) {
                    int p = c8 >> 3;
                    int i8 = (c8 & 7) << 3;
                    *(bf16x8*)&sx[(r * 130 + p + 1) * Cpad + i8] =
                        *(const bf16x8*)&src[p * Cin + i8];
                }
            }
        }
        __syncthreads();

        int chs = ch >> 5;
        for (int rs = 0; rs < 9; rs++) {
            int rrow = (rs / 3) * 130;
            int dx = rs % 3 - 1;
            int plbase = rrow + wn * 64 + (lane & 15) + dx + 1;
            #pragma unroll
            for (int ic2 = 0; ic2 < 2; ic2++) {
                int t = rs * Cdiv32 + chs + ic2;
                bf16x8 a[4], bv[4];
                size_t ai = ((abase + t) * 8 + wm * 4) * 64 + lane;
                #pragma unroll
                for (int m = 0; m < 4; m++) a[m] = Ab[ai + (size_t)m * 64];
                int c = (ic2 << 5) + ((lane >> 4) << 3);
                #pragma unroll
                for (int n = 0; n < 4; n++)
                    bv[n] = *(const bf16x8*)&sx[(plbase + n * 16) * Cpad + c];
                #pragma unroll
                for (int m = 0; m < 4; m++)
                    #pragma unroll
                    for (int n = 0; n < 4; n++)
                        acc[m][n] = __builtin_amdgcn_mfma_f32_16x16x32_bf16(
                            a[m], bv[n], acc[m][n], 0, 0, 0);
            }
        }
        __syncthreads();
    }

    // store (D: row=(lane>>4)*4+r -> out channel, col=lane&15 -> pixel)
    float* ob = out + ((size_t)b * 128) * 16384 + (size_t)y * 128 + wn * 64 + (lane & 15);
    int orow0 = wm * 64 + ((lane >> 4) << 2);
    #pragma unroll
    for (int m = 0; m < 4; m++)
        #pragma unroll
        for (int r = 0; r < 4; r++) {
            float* po = ob + (size_t)(orow0 + m * 16 + r) * 16384;
            #pragma unroll
            for (int n = 0; n < 4; n++) po[n * 16] = acc[m][n][r];
        }

    // fused per-channel partial stats: sum & sumsq over this block's 128 pixels
    #pragma unroll
    for (int m = 0; m < 4; m++)
        #pragma unroll
        for (int r = 0; r < 4; r++) {
            float s = 0.f, q = 0.f;
            #pragma unroll
            for (int n = 0; n < 4; n++) { float v = acc[m][n][r]; s += v; q += v * v; }
            #pragma unroll
            for (int msk = 1; msk < 16; msk <<= 1) {
                s += __shfl_xor(s, msk);
                q += __shfl_xor(q, msk);
            }
            if ((lane & 15) == 0) {
                int chl = m * 16 + ((lane >> 4) << 2) + r;   // 0..63 within wave's half
                sred[wid][chl][0] = s;
                sred[wid][chl][1] = q;
            }
        }
    __syncthreads();
    {
        int ch = tid >> 1, v = tid & 1;
        int wmc = ch >> 6, chl = ch & 63;
        float t = sred[wmc * 2][chl][v] + sred[wmc * 2 + 1][chl][v];
        part[((size_t)(b * 128 + y)) * 256 + tid] = t;
    }
}

// ---------------------------------------------------------------------------
// Reduce per-block partials -> per-channel mean + invstd. grid = 128.
// ---------------------------------------------------------------------------
__global__ void bnred_kernel(const float* __restrict__ part, float* __restrict__ stats) {
    int c = blockIdx.x;
    float s = 0.f, q = 0.f;
    for (int by = threadIdx.x; by < 2048; by += blockDim.x) {
        s += part[(size_t)by * 256 + 2 * c];
        q += part[(size_t)by * 256 + 2 * c + 1];
    }
    #pragma unroll
    for (int off = 32; off; off >>= 1) { s += __shfl_down(s, off); q += __shfl_down(q, off); }
    __shared__ float ss[4], qq[4];
    int lane = threadIdx.x & 63, w = threadIdx.x >> 6;
    if (!lane) { ss[w] = s; qq[w] = q; }
    __syncthreads();
    if (!threadIdx.x) {
        s = ss[0] + ss[1] + ss[2] + ss[3];
        q = qq[0] + qq[1] + qq[2] + qq[3];
        const float n = 16.f * 16384.f;
        float m = s / n;
        float var = q / n - m * m;
        stats[2 * c] = m;
        stats[2 * c + 1] = rsqrtf(var + EPS);
    }
}

// ---------------------------------------------------------------------------
// BN apply + ReLU in place (fp32 NCHW), float4-vectorized. C=128, HW=16384.
// ---------------------------------------------------------------------------
__global__ void bnapply_kernel(float4* __restrict__ buf, const float* __restrict__ stats,
                               const float* __restrict__ g, const float* __restrict__ bta,
                               size_t N4) {
    size_t idx = (size_t)blockIdx.x * blockDim.x + threadIdx.x;
    size_t stride = (size_t)gridDim.x * blockDim.x;
    for (; idx < N4; idx += stride) {
        int c = (int)((idx >> 12) & 127);
        float sc = stats[2 * c + 1] * g[c];
        float sh = bta[c] - stats[2 * c] * sc;
        float4 v = buf[idx];
        v.x = fmaxf(v.x * sc + sh, 0.f);
        v.y = fmaxf(v.y * sc + sh, 0.f);
        v.z = fmaxf(v.z * sc + sh, 0.f);
        v.w = fmaxf(v.w * sc + sh, 0.f);
        buf[idx] = v;
    }
}

// ---------------------------------------------------------------------------
extern "C" void kernel_launch(void* const* d_in, const int* in_sizes, int n_in,
                              void* d_out, int out_size, void* d_ws, size_t ws_size,
                              hipStream_t stream) {
    const int B = 16, Cin1 = 64, C = 128, H = 128, W = 128, HW = H * W;

    const float* x      = (const float*)d_in[0];
    const float* w1     = (const float*)d_in[1];
    const float* a_fc_w = (const float*)d_in[2];
    const float* a_bn_g = (const float*)d_in[3];
    const float* a_bn_b = (const float*)d_in[4];
    const float* a_ch_w = (const float*)d_in[5];
    const float* a_ch_b = (const float*)d_in[6];
    const float* a_fl_w = (const float*)d_in[7];
    const float* a_fl_b = (const float*)d_in[8];
    const float* a_sp_w = (const float*)d_in[9];
    const float* a_sp_b = (const float*)d_in[10];
    const float* a_kn_w = (const float*)d_in[11];
    const float* a_kn_b = (const float*)d_in[12];
    const float* bn1_g  = (const float*)d_in[13];
    const float* bn1_b  = (const float*)d_in[14];
    const float* w2     = (const float*)d_in[15];
    const float* b_fc_w = (const float*)d_in[16];
    const float* b_bn_g = (const float*)d_in[17];
    const float* b_bn_b = (const float*)d_in[18];
    const float* b_ch_w = (const float*)d_in[19];
    const float* b_ch_b = (const float*)d_in[20];
    const float* b_fl_w = (const float*)d_in[21];
    const float* b_fl_b = (const float*)d_in[22];
    const float* b_sp_w = (const float*)d_in[23];
    const float* b_sp_b = (const float*)d_in[24];
    const float* b_kn_w = (const float*)d_in[25];
    const float* b_kn_b = (const float*)d_in[26];
    const float* bn2_g  = (const float*)d_in[27];
    const float* bn2_b  = (const float*)d_in[28];

    float* out = (float*)d_out;
    float* ws  = (float*)d_ws;

    // workspace layout (floats)
    float* XTf   = ws;                               // xT region: 16.7M floats = 33.5M ushort
    ushort* xT   = (ushort*)XTf;
    float* WBf   = XTf + 16777216;
    ushort* WbF  = (ushort*)WBf;
    float* CPART = WBf + 1179648;                    // 2048*256 = 524288
    float* POOL  = CPART + 524288;
    float* PPART = POOL + 2048;                      // pool2 partials 32768
    float* CH    = PPART + 32768;
    float* FL    = CH + 2048;
    float* SP    = FL + 2048;
    float* KN    = SP + 160;
    float* ST    = KN + 64;

    // ---------------- layer 1 (Cin=64 -> Cout=128) ----------------
    trans_kernel<<<dim3((Cin1 / 32) * 4, H, B), 256, 0, stream>>>(x, xT, ST, nullptr, nullptr, Cin1, 0);
    pool_kernel<<<B * Cin1, 256, 0, stream>>>(x, POOL, HW);
    attn_kernel<<<1, 256, 0, stream>>>(POOL, a_fc_w, a_bn_g, a_bn_b, a_ch_w, a_ch_b,
                                       a_fl_w, a_fl_b, a_sp_w, a_sp_b, a_kn_w, a_kn_b,
                                       CH, FL, SP, KN, Cin1, C);
    int NT1 = 9 * Cin1 / 32;
    int N1 = B * NT1 * 4096;
    waggF_kernel<<<(N1 + 255) / 256, 256, 0, stream>>>(w1, CH, FL, SP, KN, WbF, C, Cin1, NT1, N1);
    conv_mfma<<<dim3(H, B), 256, 0, stream>>>(xT, WbF, out, CPART, Cin1);   // out = scratch
    bnred_kernel<<<C, 256, 0, stream>>>(CPART, ST);
    trans_kernel<<<dim3((C / 32) * 4, H, B), 256, 0, stream>>>(out, xT, ST, bn1_g, bn1_b, C, 1);

    // ---------------- layer 2 (Cin=128 -> Cout=128) ----------------
    pool2_kernel<<<dim3(B, 16), 256, 0, stream>>>(xT, PPART);
    pool2red_kernel<<<(B * C + 255) / 256, 256, 0, stream>>>(PPART, POOL, B * C);
    attn_kernel<<<1, 256, 0, stream>>>(POOL, b_fc_w, b_bn_g, b_bn_b, b_ch_w, b_ch_b,
                                       b_fl_w, b_fl_b, b_sp_w, b_sp_b, b_kn_w, b_kn_b,
                                       CH, FL, SP, KN, C, C);
    int NT2 = 9 * C / 32;
    int N2 = B * NT2 * 4096;
    waggF_kernel<<<(N2 + 255) / 256, 256, 0, stream>>>(w2, CH, FL, SP, KN, WbF, C, C, NT2, N2);
    conv_mfma<<<dim3(H, B), 256, 0, stream>>>(xT, WbF, out, CPART, C);
    bnred_kernel<<<C, 256, 0, stream>>>(CPART, ST);
    bnapply_kernel<<<2048, 256, 0, stream>>>((float4*)out, ST, bn2_g, bn2_b, (size_t)B * C * HW / 4);
}

// Round 4
// 427.023 us; speedup vs baseline: 8.0366x; 1.3027x over previous
//
#include <hip/hip_runtime.h>
#include <hip/hip_bf16.h>
#include <math.h>

#define EPS 1e-5f

typedef __attribute__((ext_vector_type(8))) short bf16x8;
typedef __attribute__((ext_vector_type(4))) float f32x4;

__device__ inline ushort f2bf(float f) {
    uint u = __float_as_uint(f);
    uint r = (u + 0x7fffu + ((u >> 16) & 1u)) >> 16;
    return (ushort)r;
}
__device__ inline float bf2f(ushort u) {
    return __uint_as_float(((uint)u) << 16);
}
__device__ inline float sigmoidf_(float x) { return 1.f / (1.f + expf(-x)); }

// ---------------------------------------------------------------------------
// Attention head (single block, 256 threads). B=16, A=16, K=4 fixed.
// ---------------------------------------------------------------------------
__global__ void attn_kernel(const float* __restrict__ pooled,
                            const float* __restrict__ fc_w,
                            const float* __restrict__ bn_g, const float* __restrict__ bn_b,
                            const float* __restrict__ ch_w, const float* __restrict__ ch_b,
                            const float* __restrict__ fl_w, const float* __restrict__ fl_b,
                            const float* __restrict__ sp_w, const float* __restrict__ sp_b,
                            const float* __restrict__ kn_w, const float* __restrict__ kn_b,
                            float* __restrict__ ch_att, float* __restrict__ fl_att,
                            float* __restrict__ sp_att, float* __restrict__ kn_att,
                            int C, int Cout) {
    const int Bb = 16, A = 16, K = 4;
    __shared__ float h[16][16];
    int tid = threadIdx.x;

    if (tid < Bb * A) {
        int b = tid >> 4, a = tid & 15;
        const float* pr = pooled + b * C;
        const float* fw = fc_w + a * C;
        float s = 0.f;
        for (int c = 0; c < C; c++) s += pr[c] * fw[c];
        h[b][a] = s;
    }
    __syncthreads();

    if (tid < A) {
        int a = tid;
        float m = 0.f;
        for (int b = 0; b < Bb; b++) m += h[b][a];
        m *= (1.f / 16.f);
        float v = 0.f;
        for (int b = 0; b < Bb; b++) { float d = h[b][a] - m; v += d * d; }
        v *= (1.f / 16.f);
        float inv = rsqrtf(v + EPS);
        float g = bn_g[a], bb = bn_b[a];
        for (int b = 0; b < Bb; b++) {
            float t = (h[b][a] - m) * inv * g + bb;
            h[b][a] = t > 0.f ? t : 0.f;
        }
    }
    __syncthreads();

    for (int idx = tid; idx < Bb * C; idx += blockDim.x) {
        int b = idx / C, c = idx % C;
        float s = ch_b[c];
        #pragma unroll
        for (int a = 0; a < A; a++) s += h[b][a] * ch_w[c * A + a];
        ch_att[idx] = sigmoidf_(s);
    }
    for (int idx = tid; idx < Bb * Cout; idx += blockDim.x) {
        int b = idx / Cout, o = idx % Cout;
        float s = fl_b[o];
        #pragma unroll
        for (int a = 0; a < A; a++) s += h[b][a] * fl_w[o * A + a];
        fl_att[idx] = sigmoidf_(s);
    }
    for (int idx = tid; idx < Bb * 9; idx += blockDim.x) {
        int b = idx / 9, r = idx % 9;
        float s = sp_b[r];
        #pragma unroll
        for (int a = 0; a < A; a++) s += h[b][a] * sp_w[r * A + a];
        sp_att[idx] = sigmoidf_(s);
    }
    if (tid < Bb) {
        int b = tid;
        float l[K], mx = -1e30f;
        #pragma unroll
        for (int k = 0; k < K; k++) {
            float s = kn_b[k];
            #pragma unroll
            for (int a = 0; a < A; a++) s += h[b][a] * kn_w[k * A + a];
            l[k] = s; mx = fmaxf(mx, s);
        }
        float den = 0.f;
        #pragma unroll
        for (int k = 0; k < K; k++) { l[k] = expf(l[k] - mx); den += l[k]; }
        #pragma unroll
        for (int k = 0; k < K; k++) kn_att[b * K + k] = l[k] / den;
    }
}

// ---------------------------------------------------------------------------
// Effective weight aggregation -> bf16 in MFMA-fragment order.
// ---------------------------------------------------------------------------
__global__ void waggF_kernel(const float* __restrict__ W4, const float* __restrict__ ch,
                             const float* __restrict__ fl, const float* __restrict__ sp,
                             const float* __restrict__ kn, ushort* __restrict__ WbF,
                             int Cout, int Cin, int NT, int N) {
    int idx = blockIdx.x * blockDim.x + threadIdx.x;
    if (idx >= N) return;
    int e = idx & 7;
    int l = (idx >> 3) & 63;
    int ot = (idx >> 9) & 7;
    int tb = idx >> 12;
    int t = tb % NT, b = tb / NT;
    int o = ot * 16 + (l & 15);
    int k = t * 32 + ((l >> 4) << 3) + e;
    int rs = k / Cin, i = k - rs * Cin;
    size_t kstride = (size_t)Cout * Cin * 9;
    const float* wp = W4 + ((size_t)o * Cin + i) * 9 + rs;
    const float* kp = kn + b * 4;
    float s = kp[0] * wp[0] + kp[1] * wp[kstride] + kp[2] * wp[2 * kstride] + kp[3] * wp[3 * kstride];
    float v = fl[b * Cout + o] * ch[b * Cin + i] * sp[b * 9 + rs] * s;
    WbF[idx] = f2bf(v);
}

// ---------------------------------------------------------------------------
// NCHW fp32 -> NHWC bf16 tiled transpose with optional BN+ReLU, and FUSED
// global-avg-pool partials (pre-rounding fp32 values).
// grid ((C/32)*(W/32), H, B), block 256.
// ppart[(b*tilesC+cbi)*32 + cl][pbi*128 + y] = sum over the 32-pixel strip.
// ---------------------------------------------------------------------------
__global__ __launch_bounds__(256) void trans_kernel(const float* __restrict__ in,
                                                    ushort* __restrict__ out,
                                                    float* __restrict__ ppart,
                                                    const float* __restrict__ stats,
                                                    const float* __restrict__ g,
                                                    const float* __restrict__ beta,
                                                    int C, int doBN) {
    int tilesC = C >> 5;
    int cbi = blockIdx.x % tilesC;
    int pbi = blockIdx.x / tilesC;
    int cb = cbi << 5, pb = pbi << 5;
    int y = blockIdx.y, b = blockIdx.z;
    __shared__ float tile[32][33];
    int t = threadIdx.x;
    int p = t & 31, c0 = t >> 5;
    float vj[4];
    #pragma unroll
    for (int j = 0; j < 4; j++) {
        int cl = c0 + j * 8;
        int c = cb + cl;
        float v = in[(((size_t)b * C + c) * 128 + y) * 128 + pb + p];
        if (doBN) {
            v = (v - stats[2 * c]) * stats[2 * c + 1] * g[c] + beta[c];
            v = fmaxf(v, 0.f);
        }
        tile[cl][p] = v;
        vj[j] = v;
    }
    // pool partial: sum over the 32 p-lanes (each c0 occupies a 32-lane half-wave)
    #pragma unroll
    for (int j = 0; j < 4; j++) {
        float s = vj[j];
        #pragma unroll
        for (int msk = 1; msk < 32; msk <<= 1) s += __shfl_xor(s, msk);
        if (p == 0) {
            int cl = c0 + j * 8;
            ppart[((size_t)((b * tilesC + cbi) * 32 + cl)) * 512 + pbi * 128 + y] = s;
        }
    }
    __syncthreads();
    int c2 = (t & 15) << 1, pp = t >> 4;
    #pragma unroll
    for (int j = 0; j < 2; j++) {
        int p2 = pp + j * 16;
        uint lo = f2bf(tile[c2][p2]);
        uint hi = f2bf(tile[c2 + 1][p2]);
        *(uint*)&out[(((size_t)b * 128 + y) * 128 + pb + p2) * C + cb + c2] = lo | (hi << 16);
    }
}

// ---------------------------------------------------------------------------
// Reduce pool partials: pool[bc] = (sum of 512 contiguous) / 16384. grid=B*C.
// ---------------------------------------------------------------------------
__global__ void poolred_kernel(const float* __restrict__ part, float* __restrict__ pool) {
    int bc = blockIdx.x;
    const float* p = part + (size_t)bc * 512;
    float s = 0.f;
    for (int i = threadIdx.x; i < 512; i += 128) s += p[i];
    #pragma unroll
    for (int off = 32; off; off >>= 1) s += __shfl_down(s, off);
    __shared__ float tmp[2];
    if ((threadIdx.x & 63) == 0) tmp[threadIdx.x >> 6] = s;
    __syncthreads();
    if (!threadIdx.x) pool[bc] = (tmp[0] + tmp[1]) * (1.f / 16384.f);
}

// ---------------------------------------------------------------------------
// Implicit-GEMM conv 3x3 pad 1 via MFMA + fused per-block BN partial stats.
// ---------------------------------------------------------------------------
__global__ __launch_bounds__(256, 2) void conv_mfma(const ushort* __restrict__ xT,
                                                    const ushort* __restrict__ WbF,
                                                    float* __restrict__ out,
                                                    float* __restrict__ part,
                                                    int Cin) {
    const int Cpad = 72;
    __shared__ short sx[3 * 130 * Cpad];    // 56,160 B
    __shared__ float sred[4][64][2];
    int y = blockIdx.x, b = blockIdx.y;
    int tid = threadIdx.x;
    int lane = tid & 63, wid = tid >> 6;
    int wm = wid >> 1, wn = wid & 1;
    int NT = (9 * Cin) >> 5;
    int Cdiv32 = Cin >> 5;

    f32x4 acc[4][4] = {};

    {
        bf16x8 z = {};
        for (int e = tid * 8; e < 3 * 130 * Cpad; e += 256 * 8)
            *(bf16x8*)&sx[e] = z;
    }
    __syncthreads();

    const bf16x8* Ab = (const bf16x8*)WbF;
    size_t abase = (size_t)b * NT;

    for (int ch = 0; ch < Cin; ch += 64) {
        for (int r = 0; r < 3; r++) {
            int yy = y + r - 1;
            if ((unsigned)yy < 128u) {
                const ushort* src = xT + ((size_t)(b * 128 + yy) * 128) * Cin + ch;
                for (int c8 = tid; c8 < 1024; c8 += 256) {
                    int p = c8 >> 3;
                    int i8 = (c8 & 7) << 3;
                    *(bf16x8*)&sx[(r * 130 + p + 1) * Cpad + i8] =
                        *(const bf16x8*)&src[p * Cin + i8];
                }
            }
        }
        __syncthreads();

        int chs = ch >> 5;
        for (int rs = 0; rs < 9; rs++) {
            int rrow = (rs / 3) * 130;
            int dx = rs % 3 - 1;
            int plbase = rrow + wn * 64 + (lane & 15) + dx + 1;
            #pragma unroll
            for (int ic2 = 0; ic2 < 2; ic2++) {
                int t = rs * Cdiv32 + chs + ic2;
                bf16x8 a[4], bv[4];
                size_t ai = ((abase + t) * 8 + wm * 4) * 64 + lane;
                #pragma unroll
                for (int m = 0; m < 4; m++) a[m] = Ab[ai + (size_t)m * 64];
                int c = (ic2 << 5) + ((lane >> 4) << 3);
                #pragma unroll
                for (int n = 0; n < 4; n++)
                    bv[n] = *(const bf16x8*)&sx[(plbase + n * 16) * Cpad + c];
                #pragma unroll
                for (int m = 0; m < 4; m++)
                    #pragma unroll
                    for (int n = 0; n < 4; n++)
                        acc[m][n] = __builtin_amdgcn_mfma_f32_16x16x32_bf16(
                            a[m], bv[n], acc[m][n], 0, 0, 0);
            }
        }
        __syncthreads();
    }

    float* ob = out + ((size_t)b * 128) * 16384 + (size_t)y * 128 + wn * 64 + (lane & 15);
    int orow0 = wm * 64 + ((lane >> 4) << 2);
    #pragma unroll
    for (int m = 0; m < 4; m++)
        #pragma unroll
        for (int r = 0; r < 4; r++) {
            float* po = ob + (size_t)(orow0 + m * 16 + r) * 16384;
            #pragma unroll
            for (int n = 0; n < 4; n++) po[n * 16] = acc[m][n][r];
        }

    #pragma unroll
    for (int m = 0; m < 4; m++)
        #pragma unroll
        for (int r = 0; r < 4; r++) {
            float s = 0.f, q = 0.f;
            #pragma unroll
            for (int n = 0; n < 4; n++) { float v = acc[m][n][r]; s += v; q += v * v; }
            #pragma unroll
            for (int msk = 1; msk < 16; msk <<= 1) {
                s += __shfl_xor(s, msk);
                q += __shfl_xor(q, msk);
            }
            if ((lane & 15) == 0) {
                int chl = m * 16 + ((lane >> 4) << 2) + r;
                sred[wid][chl][0] = s;
                sred[wid][chl][1] = q;
            }
        }
    __syncthreads();
    {
        int ch = tid >> 1, v = tid & 1;
        int wmc = ch >> 6, chl = ch & 63;
        float t = sred[wmc * 2][chl][v] + sred[wmc * 2 + 1][chl][v];
        part[((size_t)(b * 128 + y)) * 256 + tid] = t;
    }
}

// ---------------------------------------------------------------------------
// Reduce per-block partials -> per-channel mean + invstd. grid = 128.
// ---------------------------------------------------------------------------
__global__ void bnred_kernel(const float* __restrict__ part, float* __restrict__ stats) {
    int c = blockIdx.x;
    float s = 0.f, q = 0.f;
    for (int by = threadIdx.x; by < 2048; by += blockDim.x) {
        s += part[(size_t)by * 256 + 2 * c];
        q += part[(size_t)by * 256 + 2 * c + 1];
    }
    #pragma unroll
    for (int off = 32; off; off >>= 1) { s += __shfl_down(s, off); q += __shfl_down(q, off); }
    __shared__ float ss[4], qq[4];
    int lane = threadIdx.x & 63, w = threadIdx.x >> 6;
    if (!lane) { ss[w] = s; qq[w] = q; }
    __syncthreads();
    if (!threadIdx.x) {
        s = ss[0] + ss[1] + ss[2] + ss[3];
        q = qq[0] + qq[1] + qq[2] + qq[3];
        const float n = 16.f * 16384.f;
        float m = s / n;
        float var = q / n - m * m;
        stats[2 * c] = m;
        stats[2 * c + 1] = rsqrtf(var + EPS);
    }
}

// ---------------------------------------------------------------------------
// BN apply + ReLU in place (fp32 NCHW), float4-vectorized. C=128, HW=16384.
// ---------------------------------------------------------------------------
__global__ void bnapply_kernel(float4* __restrict__ buf, const float* __restrict__ stats,
                               const float* __restrict__ g, const float* __restrict__ bta,
                               size_t N4) {
    size_t idx = (size_t)blockIdx.x * blockDim.x + threadIdx.x;
    size_t stride = (size_t)gridDim.x * blockDim.x;
    for (; idx < N4; idx += stride) {
        int c = (int)((idx >> 12) & 127);
        float sc = stats[2 * c + 1] * g[c];
        float sh = bta[c] - stats[2 * c] * sc;
        float4 v = buf[idx];
        v.x = fmaxf(v.x * sc + sh, 0.f);
        v.y = fmaxf(v.y * sc + sh, 0.f);
        v.z = fmaxf(v.z * sc + sh, 0.f);
        v.w = fmaxf(v.w * sc + sh, 0.f);
        buf[idx] = v;
    }
}

// ---------------------------------------------------------------------------
extern "C" void kernel_launch(void* const* d_in, const int* in_sizes, int n_in,
                              void* d_out, int out_size, void* d_ws, size_t ws_size,
                              hipStream_t stream) {
    const int B = 16, Cin1 = 64, C = 128, H = 128, W = 128, HW = H * W;

    const float* x      = (const float*)d_in[0];
    const float* w1     = (const float*)d_in[1];
    const float* a_fc_w = (const float*)d_in[2];
    const float* a_bn_g = (const float*)d_in[3];
    const float* a_bn_b = (const float*)d_in[4];
    const float* a_ch_w = (const float*)d_in[5];
    const float* a_ch_b = (const float*)d_in[6];
    const float* a_fl_w = (const float*)d_in[7];
    const float* a_fl_b = (const float*)d_in[8];
    const float* a_sp_w = (const float*)d_in[9];
    const float* a_sp_b = (const float*)d_in[10];
    const float* a_kn_w = (const float*)d_in[11];
    const float* a_kn_b = (const float*)d_in[12];
    const float* bn1_g  = (const float*)d_in[13];
    const float* bn1_b  = (const float*)d_in[14];
    const float* w2     = (const float*)d_in[15];
    const float* b_fc_w = (const float*)d_in[16];
    const float* b_bn_g = (const float*)d_in[17];
    const float* b_bn_b = (const float*)d_in[18];
    const float* b_ch_w = (const float*)d_in[19];
    const float* b_ch_b = (const float*)d_in[20];
    const float* b_fl_w = (const float*)d_in[21];
    const float* b_fl_b = (const float*)d_in[22];
    const float* b_sp_w = (const float*)d_in[23];
    const float* b_sp_b = (const float*)d_in[24];
    const float* b_kn_w = (const float*)d_in[25];
    const float* b_kn_b = (const float*)d_in[26];
    const float* bn2_g  = (const float*)d_in[27];
    const float* bn2_b  = (const float*)d_in[28];

    float* out = (float*)d_out;
    float* ws  = (float*)d_ws;

    // workspace layout (floats)
    float* XTf   = ws;                               // xT: up to 33.5M ushort
    ushort* xT   = (ushort*)XTf;
    float* WBf   = XTf + 16777216;
    ushort* WbF  = (ushort*)WBf;
    float* CPART = WBf + 1179648;                    // conv BN partials: 524288
    float* PPART = CPART + 524288;                   // pool partials: up to 1048576
    float* POOL  = PPART + 1048576;
    float* CH    = POOL + 2048;
    float* FL    = CH + 2048;
    float* SP    = FL + 2048;
    float* KN    = SP + 160;
    float* ST    = KN + 64;

    // ---------------- layer 1 (Cin=64 -> Cout=128) ----------------
    trans_kernel<<<dim3((Cin1 / 32) * 4, H, B), 256, 0, stream>>>(x, xT, PPART, ST, nullptr, nullptr, Cin1, 0);
    poolred_kernel<<<B * Cin1, 128, 0, stream>>>(PPART, POOL);
    attn_kernel<<<1, 256, 0, stream>>>(POOL, a_fc_w, a_bn_g, a_bn_b, a_ch_w, a_ch_b,
                                       a_fl_w, a_fl_b, a_sp_w, a_sp_b, a_kn_w, a_kn_b,
                                       CH, FL, SP, KN, Cin1, C);
    int NT1 = 9 * Cin1 / 32;
    int N1 = B * NT1 * 4096;
    waggF_kernel<<<(N1 + 255) / 256, 256, 0, stream>>>(w1, CH, FL, SP, KN, WbF, C, Cin1, NT1, N1);
    conv_mfma<<<dim3(H, B), 256, 0, stream>>>(xT, WbF, out, CPART, Cin1);   // out = scratch
    bnred_kernel<<<C, 256, 0, stream>>>(CPART, ST);
    trans_kernel<<<dim3((C / 32) * 4, H, B), 256, 0, stream>>>(out, xT, PPART, ST, bn1_g, bn1_b, C, 1);

    // ---------------- layer 2 (Cin=128 -> Cout=128) ----------------
    poolred_kernel<<<B * C, 128, 0, stream>>>(PPART, POOL);
    attn_kernel<<<1, 256, 0, stream>>>(POOL, b_fc_w, b_bn_g, b_bn_b, b_ch_w, b_ch_b,
                                       b_fl_w, b_fl_b, b_sp_w, b_sp_b, b_kn_w, b_kn_b,
                                       CH, FL, SP, KN, C, C);
    int NT2 = 9 * C / 32;
    int N2 = B * NT2 * 4096;
    waggF_kernel<<<(N2 + 255) / 256, 256, 0, stream>>>(w2, CH, FL, SP, KN, WbF, C, C, NT2, N2);
    conv_mfma<<<dim3(H, B), 256, 0, stream>>>(xT, WbF, out, CPART, C);
    bnred_kernel<<<C, 256, 0, stream>>>(CPART, ST);
    bnapply_kernel<<<2048, 256, 0, stream>>>((float4*)out, ST, bn2_g, bn2_b, (size_t)B * C * HW / 4);
}

// Round 5
// 425.053 us; speedup vs baseline: 8.0738x; 1.0046x over previous
//
#include <hip/hip_runtime.h>
#include <hip/hip_bf16.h>
#include <math.h>

#define EPS 1e-5f

typedef __attribute__((ext_vector_type(8))) short bf16x8;
typedef __attribute__((ext_vector_type(4))) float f32x4;

__device__ inline ushort f2bf(float f) {
    uint u = __float_as_uint(f);
    uint r = (u + 0x7fffu + ((u >> 16) & 1u)) >> 16;
    return (ushort)r;
}
__device__ inline float bf2f(ushort u) {
    return __uint_as_float(((uint)u) << 16);
}
__device__ inline float sigmoidf_(float x) { return 1.f / (1.f + expf(-x)); }

__device__ inline void gload16(const void* g, void* l) {
    __builtin_amdgcn_global_load_lds((const __attribute__((address_space(1))) unsigned int*)g,
                                     (__attribute__((address_space(3))) unsigned int*)l,
                                     16, 0, 0);
}

// ---------------------------------------------------------------------------
// Attention head (single block, 256 threads). B=16, A=16, K=4 fixed.
// ---------------------------------------------------------------------------
__global__ void attn_kernel(const float* __restrict__ pooled,
                            const float* __restrict__ fc_w,
                            const float* __restrict__ bn_g, const float* __restrict__ bn_b,
                            const float* __restrict__ ch_w, const float* __restrict__ ch_b,
                            const float* __restrict__ fl_w, const float* __restrict__ fl_b,
                            const float* __restrict__ sp_w, const float* __restrict__ sp_b,
                            const float* __restrict__ kn_w, const float* __restrict__ kn_b,
                            float* __restrict__ ch_att, float* __restrict__ fl_att,
                            float* __restrict__ sp_att, float* __restrict__ kn_att,
                            int C, int Cout) {
    const int Bb = 16, A = 16, K = 4;
    __shared__ float h[16][16];
    int tid = threadIdx.x;

    if (tid < Bb * A) {
        int b = tid >> 4, a = tid & 15;
        const float* pr = pooled + b * C;
        const float* fw = fc_w + a * C;
        float s = 0.f;
        for (int c = 0; c < C; c++) s += pr[c] * fw[c];
        h[b][a] = s;
    }
    __syncthreads();

    if (tid < A) {
        int a = tid;
        float m = 0.f;
        for (int b = 0; b < Bb; b++) m += h[b][a];
        m *= (1.f / 16.f);
        float v = 0.f;
        for (int b = 0; b < Bb; b++) { float d = h[b][a] - m; v += d * d; }
        v *= (1.f / 16.f);
        float inv = rsqrtf(v + EPS);
        float g = bn_g[a], bb = bn_b[a];
        for (int b = 0; b < Bb; b++) {
            float t = (h[b][a] - m) * inv * g + bb;
            h[b][a] = t > 0.f ? t : 0.f;
        }
    }
    __syncthreads();

    for (int idx = tid; idx < Bb * C; idx += blockDim.x) {
        int b = idx / C, c = idx % C;
        float s = ch_b[c];
        #pragma unroll
        for (int a = 0; a < A; a++) s += h[b][a] * ch_w[c * A + a];
        ch_att[idx] = sigmoidf_(s);
    }
    for (int idx = tid; idx < Bb * Cout; idx += blockDim.x) {
        int b = idx / Cout, o = idx % Cout;
        float s = fl_b[o];
        #pragma unroll
        for (int a = 0; a < A; a++) s += h[b][a] * fl_w[o * A + a];
        fl_att[idx] = sigmoidf_(s);
    }
    for (int idx = tid; idx < Bb * 9; idx += blockDim.x) {
        int b = idx / 9, r = idx % 9;
        float s = sp_b[r];
        #pragma unroll
        for (int a = 0; a < A; a++) s += h[b][a] * sp_w[r * A + a];
        sp_att[idx] = sigmoidf_(s);
    }
    if (tid < Bb) {
        int b = tid;
        float l[K], mx = -1e30f;
        #pragma unroll
        for (int k = 0; k < K; k++) {
            float s = kn_b[k];
            #pragma unroll
            for (int a = 0; a < A; a++) s += h[b][a] * kn_w[k * A + a];
            l[k] = s; mx = fmaxf(mx, s);
        }
        float den = 0.f;
        #pragma unroll
        for (int k = 0; k < K; k++) { l[k] = expf(l[k] - mx); den += l[k]; }
        #pragma unroll
        for (int k = 0; k < K; k++) kn_att[b * K + k] = l[k] / den;
    }
}

// ---------------------------------------------------------------------------
// Effective weight aggregation -> bf16 in MFMA-fragment order.
// WbF[(((b*NT + t)*8 + ot)*64 + lane)*8 + e]: o=ot*16+(lane&15),
// k=t*32+(lane>>4)*8+e, k=rs*Cin+i, t = rs*(Cin/32) + i32.
// ---------------------------------------------------------------------------
__global__ void waggF_kernel(const float* __restrict__ W4, const float* __restrict__ ch,
                             const float* __restrict__ fl, const float* __restrict__ sp,
                             const float* __restrict__ kn, ushort* __restrict__ WbF,
                             int Cout, int Cin, int NT, int N) {
    int idx = blockIdx.x * blockDim.x + threadIdx.x;
    if (idx >= N) return;
    int e = idx & 7;
    int l = (idx >> 3) & 63;
    int ot = (idx >> 9) & 7;
    int tb = idx >> 12;
    int t = tb % NT, b = tb / NT;
    int o = ot * 16 + (l & 15);
    int k = t * 32 + ((l >> 4) << 3) + e;
    int rs = k / Cin, i = k - rs * Cin;
    size_t kstride = (size_t)Cout * Cin * 9;
    const float* wp = W4 + ((size_t)o * Cin + i) * 9 + rs;
    const float* kp = kn + b * 4;
    float s = kp[0] * wp[0] + kp[1] * wp[kstride] + kp[2] * wp[2 * kstride] + kp[3] * wp[3 * kstride];
    float v = fl[b * Cout + o] * ch[b * Cin + i] * sp[b * 9 + rs] * s;
    WbF[idx] = f2bf(v);
}

// ---------------------------------------------------------------------------
// NCHW (fp32 OR bf16) -> NHWC bf16 tiled transpose, optional BN+ReLU, fused
// global-avg-pool partials. grid ((C/32)*(W/32), H, B), block 256.
// ---------------------------------------------------------------------------
__global__ __launch_bounds__(256) void trans_kernel(const float* __restrict__ in32,
                                                    const ushort* __restrict__ in16,
                                                    ushort* __restrict__ out,
                                                    float* __restrict__ ppart,
                                                    const float* __restrict__ stats,
                                                    const float* __restrict__ g,
                                                    const float* __restrict__ beta,
                                                    int C, int doBN) {
    int tilesC = C >> 5;
    int cbi = blockIdx.x % tilesC;
    int pbi = blockIdx.x / tilesC;
    int cb = cbi << 5, pb = pbi << 5;
    int y = blockIdx.y, b = blockIdx.z;
    __shared__ float tile[32][33];
    int t = threadIdx.x;
    int p = t & 31, c0 = t >> 5;
    float vj[4];
    #pragma unroll
    for (int j = 0; j < 4; j++) {
        int cl = c0 + j * 8;
        int c = cb + cl;
        size_t idx = (((size_t)b * C + c) * 128 + y) * 128 + pb + p;
        float v = in16 ? bf2f(in16[idx]) : in32[idx];
        if (doBN) {
            v = (v - stats[2 * c]) * stats[2 * c + 1] * g[c] + beta[c];
            v = fmaxf(v, 0.f);
        }
        tile[cl][p] = v;
        vj[j] = v;
    }
    #pragma unroll
    for (int j = 0; j < 4; j++) {
        float s = vj[j];
        #pragma unroll
        for (int msk = 1; msk < 32; msk <<= 1) s += __shfl_xor(s, msk);
        if (p == 0) {
            int cl = c0 + j * 8;
            ppart[((size_t)((b * tilesC + cbi) * 32 + cl)) * 512 + pbi * 128 + y] = s;
        }
    }
    __syncthreads();
    int c2 = (t & 15) << 1, pp = t >> 4;
    #pragma unroll
    for (int j = 0; j < 2; j++) {
        int p2 = pp + j * 16;
        uint lo = f2bf(tile[c2][p2]);
        uint hi = f2bf(tile[c2 + 1][p2]);
        *(uint*)&out[(((size_t)b * 128 + y) * 128 + pb + p2) * C + cb + c2] = lo | (hi << 16);
    }
}

// ---------------------------------------------------------------------------
// Reduce pool partials: pool[bc] = (sum of 512 contiguous) / 16384. grid=B*C.
// ---------------------------------------------------------------------------
__global__ void poolred_kernel(const float* __restrict__ part, float* __restrict__ pool) {
    int bc = blockIdx.x;
    const float* p = part + (size_t)bc * 512;
    float s = 0.f;
    for (int i = threadIdx.x; i < 512; i += 128) s += p[i];
    #pragma unroll
    for (int off = 32; off; off >>= 1) s += __shfl_down(s, off);
    __shared__ float tmp[2];
    if ((threadIdx.x & 63) == 0) tmp[threadIdx.x >> 6] = s;
    __syncthreads();
    if (!threadIdx.x) pool[bc] = (tmp[0] + tmp[1]) * (1.f / 16384.f);
}

// ---------------------------------------------------------------------------
// Implicit-GEMM conv 3x3 pad 1 via MFMA.
// 32-channel chunks, double-buffered LDS staged via global_load_lds with
// source-side XOR swizzle (slot ^= (P>>1)&3, P = pixel slot 0..129).
// Output: bf16 NCHW (use16) or fp32 NCHW. Fused BN partial stats.
// ---------------------------------------------------------------------------
__global__ __launch_bounds__(256, 3) void conv_mfma(const ushort* __restrict__ xT,
                                                    const ushort* __restrict__ WbF,
                                                    float* __restrict__ outF,
                                                    ushort* __restrict__ out16,
                                                    float* __restrict__ part,
                                                    int Cin, int use16) {
    const int BUFSH = 3 * 130 * 32;              // 12,480 shorts = 24,960 B per buffer
    __shared__ short sx[2 * BUFSH];              // 49,920 B (double-buffered)
    __shared__ float sred[4][64][2];
    int y = blockIdx.x, b = blockIdx.y;
    int tid = threadIdx.x;
    int lane = tid & 63, wid = tid >> 6;
    int wm = wid >> 1, wn = wid & 1;
    int Cdiv32 = Cin >> 5;
    int NC = Cdiv32;
    int NT = 9 * Cdiv32;

    f32x4 acc[4][4] = {};

    // zero both buffers once: halo pixels (P=0,129) and OOB rows stay zero
    {
        bf16x8 z = {};
        for (int e = tid * 8; e < 2 * BUFSH; e += 2048) *(bf16x8*)&sx[e] = z;
    }
    __syncthreads();

    const size_t rowstride = (size_t)128 * Cin;

    // stage chunk ck (32 channels) into buffer bi via global_load_lds.
    // LDS dest is linear; the source channel-slot is pre-swizzled so that
    // reads at phys slot (slog ^ (P>>1)&3) see logical slot slog.
    auto stage = [&](int bi, int ck) {
        #pragma unroll
        for (int j = 0; j < 6; j++) {
            int cc = wid + 4 * j;                // 24 wave-calls: 3 rows x 8
            int r = cc >> 3, q = cc & 7;
            int yy = y + r - 1;
            if ((unsigned)yy < 128u) {
                int u = (q << 6) + lane;         // unit in row (16B units)
                int P = (u >> 2) + 1;            // pixel slot 1..128
                int slog = (u & 3) ^ ((P >> 1) & 3);
                const ushort* gp = xT + (size_t)(b * 128 + yy) * rowstride
                                      + (size_t)(P - 1) * Cin + (ck << 5) + (slog << 3);
                short* lp = &sx[bi * BUFSH + (r * 130 + 1) * 32 + (q << 9)]; // wave-uniform
                gload16(gp, lp);
            }
        }
    };

    stage(0, 0);
    __syncthreads();                              // drains vmcnt before first use

    const bf16x8* Ab = (const bf16x8*)WbF;
    size_t abase = (size_t)b * NT;

    for (int ck = 0; ck < NC; ck++) {
        if (ck + 1 < NC) stage((ck + 1) & 1, ck + 1);   // overlap stage with compute
        const short* bb = &sx[(ck & 1) * BUFSH];
        #pragma unroll 3
        for (int rs = 0; rs < 9; rs++) {
            int rr = (rs / 3) * 130;
            int dx = rs % 3 - 1;
            int t = rs * Cdiv32 + ck;
            bf16x8 a[4], bv[4];
            size_t ai = ((abase + t) * 8 + wm * 4) * 64 + lane;
            #pragma unroll
            for (int m = 0; m < 4; m++) a[m] = Ab[ai + (size_t)m * 64];
            int Pb = wn * 64 + (lane & 15) + dx + 1;
            int slog = lane >> 4;
            #pragma unroll
            for (int n = 0; n < 4; n++) {
                int P = Pb + n * 16;
                bv[n] = *(const bf16x8*)&bb[(rr + P) * 32 + ((slog ^ ((P >> 1) & 3)) << 3)];
            }
            #pragma unroll
            for (int m = 0; m < 4; m++)
                #pragma unroll
                for (int n = 0; n < 4; n++)
                    acc[m][n] = __builtin_amdgcn_mfma_f32_16x16x32_bf16(
                        a[m], bv[n], acc[m][n], 0, 0, 0);
        }
        __syncthreads();                          // drains next-chunk stage + sync
    }

    // epilogue: D row=(lane>>4)*4+r -> out channel, col=lane&15 -> pixel
    int px = wn * 64 + (lane & 15);
    int orow0 = wm * 64 + ((lane >> 4) << 2);
    if (use16) {
        #pragma unroll
        for (int m = 0; m < 4; m++)
            #pragma unroll
            for (int r = 0; r < 4; r++) {
                int oc = orow0 + m * 16 + r;
                ushort* po = out16 + ((size_t)(b * 128 + oc) * 128 + y) * 128 + px;
                #pragma unroll
                for (int n = 0; n < 4; n++) po[n * 16] = f2bf(acc[m][n][r]);
            }
    } else {
        #pragma unroll
        for (int m = 0; m < 4; m++)
            #pragma unroll
            for (int r = 0; r < 4; r++) {
                int oc = orow0 + m * 16 + r;
                float* po = outF + ((size_t)(b * 128 + oc) * 128 + y) * 128 + px;
                #pragma unroll
                for (int n = 0; n < 4; n++) po[n * 16] = acc[m][n][r];
            }
    }

    // fused per-channel partial stats over this block's 128 pixels (fp32 acc)
    #pragma unroll
    for (int m = 0; m < 4; m++)
        #pragma unroll
        for (int r = 0; r < 4; r++) {
            float s = 0.f, q = 0.f;
            #pragma unroll
            for (int n = 0; n < 4; n++) { float v = acc[m][n][r]; s += v; q += v * v; }
            #pragma unroll
            for (int msk = 1; msk < 16; msk <<= 1) {
                s += __shfl_xor(s, msk);
                q += __shfl_xor(q, msk);
            }
            if ((lane & 15) == 0) {
                int chl = m * 16 + ((lane >> 4) << 2) + r;
                sred[wid][chl][0] = s;
                sred[wid][chl][1] = q;
            }
        }
    __syncthreads();
    {
        int ch = tid >> 1, v = tid & 1;
        int wmc = ch >> 6, chl = ch & 63;
        float t2 = sred[wmc * 2][chl][v] + sred[wmc * 2 + 1][chl][v];
        part[((size_t)(b * 128 + y)) * 256 + tid] = t2;
    }
}

// ---------------------------------------------------------------------------
// Reduce per-block partials -> per-channel mean + invstd. grid = 128.
// ---------------------------------------------------------------------------
__global__ void bnred_kernel(const float* __restrict__ part, float* __restrict__ stats) {
    int c = blockIdx.x;
    float s = 0.f, q = 0.f;
    for (int by = threadIdx.x; by < 2048; by += blockDim.x) {
        s += part[(size_t)by * 256 + 2 * c];
        q += part[(size_t)by * 256 + 2 * c + 1];
    }
    #pragma unroll
    for (int off = 32; off; off >>= 1) { s += __shfl_down(s, off); q += __shfl_down(q, off); }
    __shared__ float ss[4], qq[4];
    int lane = threadIdx.x & 63, w = threadIdx.x >> 6;
    if (!lane) { ss[w] = s; qq[w] = q; }
    __syncthreads();
    if (!threadIdx.x) {
        s = ss[0] + ss[1] + ss[2] + ss[3];
        q = qq[0] + qq[1] + qq[2] + qq[3];
        const float n = 16.f * 16384.f;
        float m = s / n;
        float var = q / n - m * m;
        stats[2 * c] = m;
        stats[2 * c + 1] = rsqrtf(var + EPS);
    }
}

// ---------------------------------------------------------------------------
// BN apply + ReLU in place (fp32 NCHW), float4-vectorized. C=128, HW=16384.
// ---------------------------------------------------------------------------
__global__ void bnapply_kernel(float4* __restrict__ buf, const float* __restrict__ stats,
                               const float* __restrict__ g, const float* __restrict__ bta,
                               size_t N4) {
    size_t idx = (size_t)blockIdx.x * blockDim.x + threadIdx.x;
    size_t stride = (size_t)gridDim.x * blockDim.x;
    for (; idx < N4; idx += stride) {
        int c = (int)((idx >> 12) & 127);
        float sc = stats[2 * c + 1] * g[c];
        float sh = bta[c] - stats[2 * c] * sc;
        float4 v = buf[idx];
        v.x = fmaxf(v.x * sc + sh, 0.f);
        v.y = fmaxf(v.y * sc + sh, 0.f);
        v.z = fmaxf(v.z * sc + sh, 0.f);
        v.w = fmaxf(v.w * sc + sh, 0.f);
        buf[idx] = v;
    }
}

// ---------------------------------------------------------------------------
extern "C" void kernel_launch(void* const* d_in, const int* in_sizes, int n_in,
                              void* d_out, int out_size, void* d_ws, size_t ws_size,
                              hipStream_t stream) {
    const int B = 16, Cin1 = 64, C = 128, H = 128, W = 128, HW = H * W;

    const float* x      = (const float*)d_in[0];
    const float* w1     = (const float*)d_in[1];
    const float* a_fc_w = (const float*)d_in[2];
    const float* a_bn_g = (const float*)d_in[3];
    const float* a_bn_b = (const float*)d_in[4];
    const float* a_ch_w = (const float*)d_in[5];
    const float* a_ch_b = (const float*)d_in[6];
    const float* a_fl_w = (const float*)d_in[7];
    const float* a_fl_b = (const float*)d_in[8];
    const float* a_sp_w = (const float*)d_in[9];
    const float* a_sp_b = (const float*)d_in[10];
    const float* a_kn_w = (const float*)d_in[11];
    const float* a_kn_b = (const float*)d_in[12];
    const float* bn1_g  = (const float*)d_in[13];
    const float* bn1_b  = (const float*)d_in[14];
    const float* w2     = (const float*)d_in[15];
    const float* b_fc_w = (const float*)d_in[16];
    const float* b_bn_g = (const float*)d_in[17];
    const float* b_bn_b = (const float*)d_in[18];
    const float* b_ch_w = (const float*)d_in[19];
    const float* b_ch_b = (const float*)d_in[20];
    const float* b_fl_w = (const float*)d_in[21];
    const float* b_fl_b = (const float*)d_in[22];
    const float* b_sp_w = (const float*)d_in[23];
    const float* b_sp_b = (const float*)d_in[24];
    const float* b_kn_w = (const float*)d_in[25];
    const float* b_kn_b = (const float*)d_in[26];
    const float* bn2_g  = (const float*)d_in[27];
    const float* bn2_b  = (const float*)d_in[28];

    float* out = (float*)d_out;
    float* ws  = (float*)d_ws;

    // workspace layout (floats) — same footprint as round 4 (~78 MB)
    float* XTf   = ws;                               // xT NHWC bf16: up to 33.5M ushort
    ushort* xT   = (ushort*)XTf;
    float* WBf   = XTf + 16777216;
    ushort* WbF  = (ushort*)WBf;
    float* CPART = WBf + 1179648;                    // conv BN partials
    float* PPART = CPART + 524288;                   // pool partials
    float* POOL  = PPART + 1048576;
    float* CH    = POOL + 2048;
    float* FL    = CH + 2048;
    float* SP    = FL + 2048;
    float* KN    = SP + 160;
    float* ST    = KN + 64;

    ushort* xhat1 = (ushort*)out;                    // d_out as bf16 NCHW scratch (layer 1)

    // ---------------- layer 1 (Cin=64 -> Cout=128) ----------------
    trans_kernel<<<dim3((Cin1 / 32) * 4, H, B), 256, 0, stream>>>(
        x, nullptr, xT, PPART, ST, nullptr, nullptr, Cin1, 0);
    poolred_kernel<<<B * Cin1, 128, 0, stream>>>(PPART, POOL);
    attn_kernel<<<1, 256, 0, stream>>>(POOL, a_fc_w, a_bn_g, a_bn_b, a_ch_w, a_ch_b,
                                       a_fl_w, a_fl_b, a_sp_w, a_sp_b, a_kn_w, a_kn_b,
                                       CH, FL, SP, KN, Cin1, C);
    int NT1 = 9 * Cin1 / 32;
    int N1 = B * NT1 * 4096;
    waggF_kernel<<<(N1 + 255) / 256, 256, 0, stream>>>(w1, CH, FL, SP, KN, WbF, C, Cin1, NT1, N1);
    conv_mfma<<<dim3(H, B), 256, 0, stream>>>(xT, WbF, nullptr, xhat1, CPART, Cin1, 1);
    bnred_kernel<<<C, 256, 0, stream>>>(CPART, ST);
    trans_kernel<<<dim3((C / 32) * 4, H, B), 256, 0, stream>>>(
        nullptr, xhat1, xT, PPART, ST, bn1_g, bn1_b, C, 1);

    // ---------------- layer 2 (Cin=128 -> Cout=128) ----------------
    poolred_kernel<<<B * C, 128, 0, stream>>>(PPART, POOL);
    attn_kernel<<<1, 256, 0, stream>>>(POOL, b_fc_w, b_bn_g, b_bn_b, b_ch_w, b_ch_b,
                                       b_fl_w, b_fl_b, b_sp_w, b_sp_b, b_kn_w, b_kn_b,
                                       CH, FL, SP, KN, C, C);
    int NT2 = 9 * C / 32;
    int N2 = B * NT2 * 4096;
    waggF_kernel<<<(N2 + 255) / 256, 256, 0, stream>>>(w2, CH, FL, SP, KN, WbF, C, C, NT2, N2);
    conv_mfma<<<dim3(H, B), 256, 0, stream>>>(xT, WbF, out, nullptr, CPART, C, 0);
    bnred_kernel<<<C, 256, 0, stream>>>(CPART, ST);
    bnapply_kernel<<<2048, 256, 0, stream>>>((float4*)out, ST, bn2_g, bn2_b, (size_t)B * C * HW / 4);
}

// Round 6
// 377.925 us; speedup vs baseline: 9.0807x; 1.1247x over previous
//
#include <hip/hip_runtime.h>
#include <hip/hip_bf16.h>
#include <math.h>

#define EPS 1e-5f

typedef __attribute__((ext_vector_type(8))) short bf16x8;
typedef __attribute__((ext_vector_type(4))) float f32x4;

__device__ inline ushort f2bf(float f) {
    uint u = __float_as_uint(f);
    uint r = (u + 0x7fffu + ((u >> 16) & 1u)) >> 16;
    return (ushort)r;
}
__device__ inline float bf2f(ushort u) {
    return __uint_as_float(((uint)u) << 16);
}
__device__ inline float sigmoidf_(float x) { return 1.f / (1.f + expf(-x)); }

__device__ inline void gload16(const void* g, void* l) {
    __builtin_amdgcn_global_load_lds((const __attribute__((address_space(1))) unsigned int*)g,
                                     (__attribute__((address_space(3))) unsigned int*)l,
                                     16, 0, 0);
}

// ---------------------------------------------------------------------------
// Attention head (single block, 256 threads). B=16, A=16, K=4 fixed.
// ---------------------------------------------------------------------------
__global__ void attn_kernel(const float* __restrict__ pooled,
                            const float* __restrict__ fc_w,
                            const float* __restrict__ bn_g, const float* __restrict__ bn_b,
                            const float* __restrict__ ch_w, const float* __restrict__ ch_b,
                            const float* __restrict__ fl_w, const float* __restrict__ fl_b,
                            const float* __restrict__ sp_w, const float* __restrict__ sp_b,
                            const float* __restrict__ kn_w, const float* __restrict__ kn_b,
                            float* __restrict__ ch_att, float* __restrict__ fl_att,
                            float* __restrict__ sp_att, float* __restrict__ kn_att,
                            int C, int Cout) {
    const int Bb = 16, A = 16, K = 4;
    __shared__ float h[16][16];
    int tid = threadIdx.x;

    if (tid < Bb * A) {
        int b = tid >> 4, a = tid & 15;
        const float* pr = pooled + b * C;
        const float* fw = fc_w + a * C;
        float s = 0.f;
        for (int c = 0; c < C; c++) s += pr[c] * fw[c];
        h[b][a] = s;
    }
    __syncthreads();

    if (tid < A) {
        int a = tid;
        float m = 0.f;
        for (int b = 0; b < Bb; b++) m += h[b][a];
        m *= (1.f / 16.f);
        float v = 0.f;
        for (int b = 0; b < Bb; b++) { float d = h[b][a] - m; v += d * d; }
        v *= (1.f / 16.f);
        float inv = rsqrtf(v + EPS);
        float g = bn_g[a], bb = bn_b[a];
        for (int b = 0; b < Bb; b++) {
            float t = (h[b][a] - m) * inv * g + bb;
            h[b][a] = t > 0.f ? t : 0.f;
        }
    }
    __syncthreads();

    for (int idx = tid; idx < Bb * C; idx += blockDim.x) {
        int b = idx / C, c = idx % C;
        float s = ch_b[c];
        #pragma unroll
        for (int a = 0; a < A; a++) s += h[b][a] * ch_w[c * A + a];
        ch_att[idx] = sigmoidf_(s);
    }
    for (int idx = tid; idx < Bb * Cout; idx += blockDim.x) {
        int b = idx / Cout, o = idx % Cout;
        float s = fl_b[o];
        #pragma unroll
        for (int a = 0; a < A; a++) s += h[b][a] * fl_w[o * A + a];
        fl_att[idx] = sigmoidf_(s);
    }
    for (int idx = tid; idx < Bb * 9; idx += blockDim.x) {
        int b = idx / 9, r = idx % 9;
        float s = sp_b[r];
        #pragma unroll
        for (int a = 0; a < A; a++) s += h[b][a] * sp_w[r * A + a];
        sp_att[idx] = sigmoidf_(s);
    }
    if (tid < Bb) {
        int b = tid;
        float l[K], mx = -1e30f;
        #pragma unroll
        for (int k = 0; k < K; k++) {
            float s = kn_b[k];
            #pragma unroll
            for (int a = 0; a < A; a++) s += h[b][a] * kn_w[k * A + a];
            l[k] = s; mx = fmaxf(mx, s);
        }
        float den = 0.f;
        #pragma unroll
        for (int k = 0; k < K; k++) { l[k] = expf(l[k] - mx); den += l[k]; }
        #pragma unroll
        for (int k = 0; k < K; k++) kn_att[b * K + k] = l[k] / den;
    }
}

// ---------------------------------------------------------------------------
// Effective weight aggregation -> bf16 in MFMA-fragment order.
// ---------------------------------------------------------------------------
__global__ void waggF_kernel(const float* __restrict__ W4, const float* __restrict__ ch,
                             const float* __restrict__ fl, const float* __restrict__ sp,
                             const float* __restrict__ kn, ushort* __restrict__ WbF,
                             int Cout, int Cin, int NT, int N) {
    int idx = blockIdx.x * blockDim.x + threadIdx.x;
    if (idx >= N) return;
    int e = idx & 7;
    int l = (idx >> 3) & 63;
    int ot = (idx >> 9) & 7;
    int tb = idx >> 12;
    int t = tb % NT, b = tb / NT;
    int o = ot * 16 + (l & 15);
    int k = t * 32 + ((l >> 4) << 3) + e;
    int rs = k / Cin, i = k - rs * Cin;
    size_t kstride = (size_t)Cout * Cin * 9;
    const float* wp = W4 + ((size_t)o * Cin + i) * 9 + rs;
    const float* kp = kn + b * 4;
    float s = kp[0] * wp[0] + kp[1] * wp[kstride] + kp[2] * wp[2 * kstride] + kp[3] * wp[3 * kstride];
    float v = fl[b * Cout + o] * ch[b * Cin + i] * sp[b * 9 + rs] * s;
    WbF[idx] = f2bf(v);
}

// ---------------------------------------------------------------------------
// NCHW (fp32 OR bf16) -> NHWC bf16 tiled transpose, optional BN+ReLU, fused
// global-avg-pool partials. grid ((C/32)*(W/32), H, B), block 256.
// ---------------------------------------------------------------------------
__global__ __launch_bounds__(256) void trans_kernel(const float* __restrict__ in32,
                                                    const ushort* __restrict__ in16,
                                                    ushort* __restrict__ out,
                                                    float* __restrict__ ppart,
                                                    const float* __restrict__ stats,
                                                    const float* __restrict__ g,
                                                    const float* __restrict__ beta,
                                                    int C, int doBN) {
    int tilesC = C >> 5;
    int cbi = blockIdx.x % tilesC;
    int pbi = blockIdx.x / tilesC;
    int cb = cbi << 5, pb = pbi << 5;
    int y = blockIdx.y, b = blockIdx.z;
    __shared__ float tile[32][33];
    int t = threadIdx.x;
    int p = t & 31, c0 = t >> 5;
    float vj[4];
    #pragma unroll
    for (int j = 0; j < 4; j++) {
        int cl = c0 + j * 8;
        int c = cb + cl;
        size_t idx = (((size_t)b * C + c) * 128 + y) * 128 + pb + p;
        float v = in16 ? bf2f(in16[idx]) : in32[idx];
        if (doBN) {
            v = (v - stats[2 * c]) * stats[2 * c + 1] * g[c] + beta[c];
            v = fmaxf(v, 0.f);
        }
        tile[cl][p] = v;
        vj[j] = v;
    }
    #pragma unroll
    for (int j = 0; j < 4; j++) {
        float s = vj[j];
        #pragma unroll
        for (int msk = 1; msk < 32; msk <<= 1) s += __shfl_xor(s, msk);
        if (p == 0) {
            int cl = c0 + j * 8;
            ppart[((size_t)((b * tilesC + cbi) * 32 + cl)) * 512 + pbi * 128 + y] = s;
        }
    }
    __syncthreads();
    int c2 = (t & 15) << 1, pp = t >> 4;
    #pragma unroll
    for (int j = 0; j < 2; j++) {
        int p2 = pp + j * 16;
        uint lo = f2bf(tile[c2][p2]);
        uint hi = f2bf(tile[c2 + 1][p2]);
        *(uint*)&out[(((size_t)b * 128 + y) * 128 + pb + p2) * C + cb + c2] = lo | (hi << 16);
    }
}

// ---------------------------------------------------------------------------
// Reduce pool partials. grid=B*C.
// ---------------------------------------------------------------------------
__global__ void poolred_kernel(const float* __restrict__ part, float* __restrict__ pool) {
    int bc = blockIdx.x;
    const float* p = part + (size_t)bc * 512;
    float s = 0.f;
    for (int i = threadIdx.x; i < 512; i += 128) s += p[i];
    #pragma unroll
    for (int off = 32; off; off >>= 1) s += __shfl_down(s, off);
    __shared__ float tmp[2];
    if ((threadIdx.x & 63) == 0) tmp[threadIdx.x >> 6] = s;
    __syncthreads();
    if (!threadIdx.x) pool[bc] = (tmp[0] + tmp[1]) * (1.f / 16384.f);
}

// ---------------------------------------------------------------------------
// Implicit-GEMM conv 3x3 pad 1 via MFMA. 1D grid of 2048 with XCD-aware
// swizzle: each XCD owns 2 contiguous samples x all rows -> y-halo rows and
// per-sample weights are L2-resident. 32-ch chunks, double-buffered
// global_load_lds staging with source-side XOR swizzle.
// ---------------------------------------------------------------------------
__global__ __launch_bounds__(256, 3) void conv_mfma(const ushort* __restrict__ xT,
                                                    const ushort* __restrict__ WbF,
                                                    float* __restrict__ outF,
                                                    ushort* __restrict__ out16,
                                                    float* __restrict__ part,
                                                    int Cin, int use16) {
    const int BUFSH = 3 * 130 * 32;
    __shared__ short sx[2 * BUFSH];
    __shared__ float sred[4][64][2];
    // XCD swizzle: id%8 = XCD; give each XCD a contiguous 256-block chunk
    int id = blockIdx.x;
    int swz = (id & 7) * (gridDim.x >> 3) + (id >> 3);
    int y = swz & 127, b = swz >> 7;
    int tid = threadIdx.x;
    int lane = tid & 63, wid = tid >> 6;
    int wm = wid >> 1, wn = wid & 1;
    int Cdiv32 = Cin >> 5;
    int NC = Cdiv32;
    int NT = 9 * Cdiv32;

    f32x4 acc[4][4] = {};

    {
        bf16x8 z = {};
        for (int e = tid * 8; e < 2 * BUFSH; e += 2048) *(bf16x8*)&sx[e] = z;
    }
    __syncthreads();

    const size_t rowstride = (size_t)128 * Cin;

    auto stage = [&](int bi, int ck) {
        #pragma unroll
        for (int j = 0; j < 6; j++) {
            int cc = wid + 4 * j;                // 24 wave-calls: 3 rows x 8
            int r = cc >> 3, q = cc & 7;
            int yy = y + r - 1;
            if ((unsigned)yy < 128u) {
                int u = (q << 6) + lane;
                int P = (u >> 2) + 1;
                int slog = (u & 3) ^ ((P >> 1) & 3);
                const ushort* gp = xT + (size_t)(b * 128 + yy) * rowstride
                                      + (size_t)(P - 1) * Cin + (ck << 5) + (slog << 3);
                short* lp = &sx[bi * BUFSH + (r * 130 + 1) * 32 + (q << 9)];
                gload16(gp, lp);
            }
        }
    };

    stage(0, 0);
    __syncthreads();

    const bf16x8* Ab = (const bf16x8*)WbF;
    size_t abase = (size_t)b * NT;

    for (int ck = 0; ck < NC; ck++) {
        if (ck + 1 < NC) stage((ck + 1) & 1, ck + 1);
        const short* bb = &sx[(ck & 1) * BUFSH];
        #pragma unroll
        for (int rs = 0; rs < 9; rs++) {
            int rr = (rs / 3) * 130;
            int dx = rs % 3 - 1;
            int t = rs * Cdiv32 + ck;
            bf16x8 a[4], bv[4];
            size_t ai = ((abase + t) * 8 + wm * 4) * 64 + lane;
            #pragma unroll
            for (int m = 0; m < 4; m++) a[m] = Ab[ai + (size_t)m * 64];
            int Pb = wn * 64 + (lane & 15) + dx + 1;
            int slog = lane >> 4;
            #pragma unroll
            for (int n = 0; n < 4; n++) {
                int P = Pb + n * 16;
                bv[n] = *(const bf16x8*)&bb[(rr + P) * 32 + ((slog ^ ((P >> 1) & 3)) << 3)];
            }
            #pragma unroll
            for (int m = 0; m < 4; m++)
                #pragma unroll
                for (int n = 0; n < 4; n++)
                    acc[m][n] = __builtin_amdgcn_mfma_f32_16x16x32_bf16(
                        a[m], bv[n], acc[m][n], 0, 0, 0);
        }
        __syncthreads();
    }

    // epilogue
    int px = wn * 64 + (lane & 15);
    int orow0 = wm * 64 + ((lane >> 4) << 2);
    if (use16) {
        #pragma unroll
        for (int m = 0; m < 4; m++)
            #pragma unroll
            for (int r = 0; r < 4; r++) {
                int oc = orow0 + m * 16 + r;
                ushort* po = out16 + ((size_t)(b * 128 + oc) * 128 + y) * 128 + px;
                #pragma unroll
                for (int n = 0; n < 4; n++) po[n * 16] = f2bf(acc[m][n][r]);
            }
    } else {
        #pragma unroll
        for (int m = 0; m < 4; m++)
            #pragma unroll
            for (int r = 0; r < 4; r++) {
                int oc = orow0 + m * 16 + r;
                float* po = outF + ((size_t)(b * 128 + oc) * 128 + y) * 128 + px;
                #pragma unroll
                for (int n = 0; n < 4; n++) po[n * 16] = acc[m][n][r];
            }
    }

    // fused per-channel partial stats (exact fp32 accumulators)
    #pragma unroll
    for (int m = 0; m < 4; m++)
        #pragma unroll
        for (int r = 0; r < 4; r++) {
            float s = 0.f, q = 0.f;
            #pragma unroll
            for (int n = 0; n < 4; n++) { float v = acc[m][n][r]; s += v; q += v * v; }
            #pragma unroll
            for (int msk = 1; msk < 16; msk <<= 1) {
                s += __shfl_xor(s, msk);
                q += __shfl_xor(q, msk);
            }
            if ((lane & 15) == 0) {
                int chl = m * 16 + ((lane >> 4) << 2) + r;
                sred[wid][chl][0] = s;
                sred[wid][chl][1] = q;
            }
        }
    __syncthreads();
    {
        int ch = tid >> 1, v = tid & 1;
        int wmc = ch >> 6, chl = ch & 63;
        float t2 = sred[wmc * 2][chl][v] + sred[wmc * 2 + 1][chl][v];
        part[((size_t)(b * 128 + y)) * 256 + tid] = t2;
    }
}

// ---------------------------------------------------------------------------
// Reduce per-block partials -> per-channel mean + invstd. grid = 128.
// ---------------------------------------------------------------------------
__global__ void bnred_kernel(const float* __restrict__ part, float* __restrict__ stats) {
    int c = blockIdx.x;
    float s = 0.f, q = 0.f;
    for (int by = threadIdx.x; by < 2048; by += blockDim.x) {
        s += part[(size_t)by * 256 + 2 * c];
        q += part[(size_t)by * 256 + 2 * c + 1];
    }
    #pragma unroll
    for (int off = 32; off; off >>= 1) { s += __shfl_down(s, off); q += __shfl_down(q, off); }
    __shared__ float ss[4], qq[4];
    int lane = threadIdx.x & 63, w = threadIdx.x >> 6;
    if (!lane) { ss[w] = s; qq[w] = q; }
    __syncthreads();
    if (!threadIdx.x) {
        s = ss[0] + ss[1] + ss[2] + ss[3];
        q = qq[0] + qq[1] + qq[2] + qq[3];
        const float n = 16.f * 16384.f;
        float m = s / n;
        float var = q / n - m * m;
        stats[2 * c] = m;
        stats[2 * c + 1] = rsqrtf(var + EPS);
    }
}

// ---------------------------------------------------------------------------
// BN apply + ReLU, fp32 NCHW in place. C=128, HW=16384.
// ---------------------------------------------------------------------------
__global__ void bnapply_kernel(float4* __restrict__ buf, const float* __restrict__ stats,
                               const float* __restrict__ g, const float* __restrict__ bta,
                               size_t N4) {
    size_t idx = (size_t)blockIdx.x * blockDim.x + threadIdx.x;
    size_t stride = (size_t)gridDim.x * blockDim.x;
    for (; idx < N4; idx += stride) {
        int c = (int)((idx >> 12) & 127);
        float sc = stats[2 * c + 1] * g[c];
        float sh = bta[c] - stats[2 * c] * sc;
        float4 v = buf[idx];
        v.x = fmaxf(v.x * sc + sh, 0.f);
        v.y = fmaxf(v.y * sc + sh, 0.f);
        v.z = fmaxf(v.z * sc + sh, 0.f);
        v.w = fmaxf(v.w * sc + sh, 0.f);
        buf[idx] = v;
    }
}

// ---------------------------------------------------------------------------
// BN apply + ReLU: bf16 NCHW in -> fp32 NCHW out. C=128, HW=16384.
// ---------------------------------------------------------------------------
__global__ void bnapply16_kernel(const ushort* __restrict__ in, float4* __restrict__ out,
                                 const float* __restrict__ stats,
                                 const float* __restrict__ g, const float* __restrict__ bta,
                                 size_t N4) {
    size_t idx = (size_t)blockIdx.x * blockDim.x + threadIdx.x;
    size_t stride = (size_t)gridDim.x * blockDim.x;
    for (; idx < N4; idx += stride) {
        int c = (int)((idx >> 12) & 127);
        float sc = stats[2 * c + 1] * g[c];
        float sh = bta[c] - stats[2 * c] * sc;
        ushort4 u = *(const ushort4*)&in[idx * 4];
        float4 v;
        v.x = fmaxf(bf2f(u.x) * sc + sh, 0.f);
        v.y = fmaxf(bf2f(u.y) * sc + sh, 0.f);
        v.z = fmaxf(bf2f(u.z) * sc + sh, 0.f);
        v.w = fmaxf(bf2f(u.w) * sc + sh, 0.f);
        out[idx] = v;
    }
}

// ---------------------------------------------------------------------------
extern "C" void kernel_launch(void* const* d_in, const int* in_sizes, int n_in,
                              void* d_out, int out_size, void* d_ws, size_t ws_size,
                              hipStream_t stream) {
    const int B = 16, Cin1 = 64, C = 128, H = 128, W = 128, HW = H * W;

    const float* x      = (const float*)d_in[0];
    const float* w1     = (const float*)d_in[1];
    const float* a_fc_w = (const float*)d_in[2];
    const float* a_bn_g = (const float*)d_in[3];
    const float* a_bn_b = (const float*)d_in[4];
    const float* a_ch_w = (const float*)d_in[5];
    const float* a_ch_b = (const float*)d_in[6];
    const float* a_fl_w = (const float*)d_in[7];
    const float* a_fl_b = (const float*)d_in[8];
    const float* a_sp_w = (const float*)d_in[9];
    const float* a_sp_b = (const float*)d_in[10];
    const float* a_kn_w = (const float*)d_in[11];
    const float* a_kn_b = (const float*)d_in[12];
    const float* bn1_g  = (const float*)d_in[13];
    const float* bn1_b  = (const float*)d_in[14];
    const float* w2     = (const float*)d_in[15];
    const float* b_fc_w = (const float*)d_in[16];
    const float* b_bn_g = (const float*)d_in[17];
    const float* b_bn_b = (const float*)d_in[18];
    const float* b_ch_w = (const float*)d_in[19];
    const float* b_ch_b = (const float*)d_in[20];
    const float* b_fl_w = (const float*)d_in[21];
    const float* b_fl_b = (const float*)d_in[22];
    const float* b_sp_w = (const float*)d_in[23];
    const float* b_sp_b = (const float*)d_in[24];
    const float* b_kn_w = (const float*)d_in[25];
    const float* b_kn_b = (const float*)d_in[26];
    const float* bn2_g  = (const float*)d_in[27];
    const float* bn2_b  = (const float*)d_in[28];

    float* out = (float*)d_out;
    float* ws  = (float*)d_ws;

    // workspace layout (floats)
    float* XTf   = ws;                               // xT NHWC bf16: 33.5M ushort
    ushort* xT   = (ushort*)XTf;
    float* WBf   = XTf + 16777216;
    ushort* WbF  = (ushort*)WBf;
    float* CPART = WBf + 1179648;
    float* PPART = CPART + 524288;
    float* POOL  = PPART + 1048576;
    float* CH    = POOL + 2048;
    float* FL    = CH + 2048;
    float* SP    = FL + 2048;
    float* KN    = SP + 160;
    float* ST    = KN + 64;
    float* XH2f  = ST + 256;                         // optional bf16 conv2 output
    ushort* xhat2 = (ushort*)XH2f;

    // does ws have room for the bf16 conv2 intermediate (16.7M extra floats)?
    size_t need = ((size_t)(XH2f - ws) + 16777216) * sizeof(float);
    int fit2 = ws_size >= need;

    ushort* xhat1 = (ushort*)out;                    // d_out as bf16 NCHW scratch (layer 1)

    // ---------------- layer 1 (Cin=64 -> Cout=128) ----------------
    trans_kernel<<<dim3((Cin1 / 32) * 4, H, B), 256, 0, stream>>>(
        x, nullptr, xT, PPART, ST, nullptr, nullptr, Cin1, 0);
    poolred_kernel<<<B * Cin1, 128, 0, stream>>>(PPART, POOL);
    attn_kernel<<<1, 256, 0, stream>>>(POOL, a_fc_w, a_bn_g, a_bn_b, a_ch_w, a_ch_b,
                                       a_fl_w, a_fl_b, a_sp_w, a_sp_b, a_kn_w, a_kn_b,
                                       CH, FL, SP, KN, Cin1, C);
    int NT1 = 9 * Cin1 / 32;
    int N1 = B * NT1 * 4096;
    waggF_kernel<<<(N1 + 255) / 256, 256, 0, stream>>>(w1, CH, FL, SP, KN, WbF, C, Cin1, NT1, N1);
    conv_mfma<<<H * B, 256, 0, stream>>>(xT, WbF, nullptr, xhat1, CPART, Cin1, 1);
    bnred_kernel<<<C, 256, 0, stream>>>(CPART, ST);
    trans_kernel<<<dim3((C / 32) * 4, H, B), 256, 0, stream>>>(
        nullptr, xhat1, xT, PPART, ST, bn1_g, bn1_b, C, 1);

    // ---------------- layer 2 (Cin=128 -> Cout=128) ----------------
    poolred_kernel<<<B * C, 128, 0, stream>>>(PPART, POOL);
    attn_kernel<<<1, 256, 0, stream>>>(POOL, b_fc_w, b_bn_g, b_bn_b, b_ch_w, b_ch_b,
                                       b_fl_w, b_fl_b, b_sp_w, b_sp_b, b_kn_w, b_kn_b,
                                       CH, FL, SP, KN, C, C);
    int NT2 = 9 * C / 32;
    int N2 = B * NT2 * 4096;
    waggF_kernel<<<(N2 + 255) / 256, 256, 0, stream>>>(w2, CH, FL, SP, KN, WbF, C, C, NT2, N2);
    if (fit2) {
        conv_mfma<<<H * B, 256, 0, stream>>>(xT, WbF, nullptr, xhat2, CPART, C, 1);
        bnred_kernel<<<C, 256, 0, stream>>>(CPART, ST);
        bnapply16_kernel<<<2048, 256, 0, stream>>>(xhat2, (float4*)out, ST, bn2_g, bn2_b,
                                                   (size_t)B * C * HW / 4);
    } else {
        conv_mfma<<<H * B, 256, 0, stream>>>(xT, WbF, out, nullptr, CPART, C, 0);
        bnred_kernel<<<C, 256, 0, stream>>>(CPART, ST);
        bnapply_kernel<<<2048, 256, 0, stream>>>((float4*)out, ST, bn2_g, bn2_b,
                                                 (size_t)B * C * HW / 4);
    }
}